// Round 4
// baseline (3408.020 us; speedup 1.0000x reference)
//
#include <hip/hip_runtime.h>
#include <hip/hip_fp16.h>

// LSTM Autoencoder: B=256, T=128, I=512, H=1024, E=256
// Round-6: encoder restructured to 8 row-groups x 32 col-blocks of 512 threads
// (was 4 x 64 x 256). Halves the per-step all-to-all group (32 consumers/rg)
// and the coherent h traffic (16 MB/step), attacking the max-of-N straggler
// chain that rounds 1-3 showed is the real limiter. Load path keeps the
// measured-good sc1 dwordx2 protocol; 2-slot h ring; per-wave barrier-free
// flag publication (8 adds/block/step).
// Decoder: verbatim round-1/2 dataflow sentinel kernel (measured ~640us).

#define B_ 256
#define T_ 128
#define I_ 512
#define H_ 1024
#define E_ 256

#define ENC_STEP 262144   // fp16 elems per encoder h slot (256x1024)
#define DEC_STEP 131072   // fp16 elems per decoder h slot (256x512)
#define SENT32 0x7C7C7C7Cu   // two fp16 NaNs; unreachable by real h pairs

typedef _Float16 half8 __attribute__((ext_vector_type(8)));
typedef float floatx4 __attribute__((ext_vector_type(4)));

__device__ __forceinline__ float sigmoidf_(float x) { return 1.0f / (1.0f + __expf(-x)); }
__device__ __forceinline__ float tanhf_(float x) {
    x = fminf(fmaxf(x, -15.0f), 15.0f);
    float e = __expf(2.0f * x);
    return (e - 1.0f) / (e + 1.0f);
}

union HU { unsigned long long u[2]; unsigned v[4]; half8 h; };

// coherent 16B load as 2x u64 relaxed-agent atomics (global_load_dwordx2 sc0 sc1)
__device__ __forceinline__ void ld_chunk(const _Float16* p, HU& v) {
    const unsigned long long* q = (const unsigned long long*)p;
    v.u[0] = __hip_atomic_load(q,     __ATOMIC_RELAXED, __HIP_MEMORY_SCOPE_AGENT);
    v.u[1] = __hip_atomic_load(q + 1, __ATOMIC_RELAXED, __HIP_MEMORY_SCOPE_AGENT);
}
__device__ __forceinline__ int chunk_ok(const HU& v) {
    return (int)((v.v[0] != SENT32) & (v.v[1] != SENT32)
               & (v.v[2] != SENT32) & (v.v[3] != SENT32));
}
template <int STRIDE>
__device__ __forceinline__ void load_grp(const _Float16* base, HU v[4]) {
#pragma unroll
    for (int m = 0; m < 4; ++m) ld_chunk(base + (size_t)m * STRIDE, v[m]);
}
template <int STRIDE>
__device__ __forceinline__ void fix_grp(const _Float16* base, HU v[4]) {
    while (!(chunk_ok(v[0]) & chunk_ok(v[1]) & chunk_ok(v[2]) & chunk_ok(v[3]))) {
        __builtin_amdgcn_s_sleep(1);
        load_grp<STRIDE>(base, v);
    }
}

__device__ __forceinline__ half8 ldg_h8_sc1(const _Float16* p) {
    HU v; ld_chunk(p, v); return v.h;
}
__device__ __forceinline__ void stg_h2_sc1(_Float16* p, float a, float b) {
    union { _Float16 h[2]; unsigned int u; } v;
    v.h[0] = (_Float16)a; v.h[1] = (_Float16)b;
    __hip_atomic_store((unsigned int*)p, v.u, __ATOMIC_RELAXED, __HIP_MEMORY_SCOPE_AGENT);
}
__device__ __forceinline__ void stg_u32_sc1(_Float16* p, unsigned v) {
    __hip_atomic_store((unsigned int*)p, v, __ATOMIC_RELAXED, __HIP_MEMORY_SCOPE_AGENT);
}
__device__ __forceinline__ void wait_vm0() {
    asm volatile("s_waitcnt vmcnt(0)" ::: "memory");
}
__device__ __forceinline__ void poll_rg(int* flags, int rgbase, int lane, int target) {
    while (__hip_atomic_load(&flags[rgbase + lane], __ATOMIC_RELAXED, __HIP_MEMORY_SCOPE_AGENT) < target)
        __builtin_amdgcn_s_sleep(1);
    asm volatile("" ::: "memory");
}

// ---------------- x -> MFMA A-fragment layout (once) ----------------
__global__ void shuffle_x_kernel(const float* __restrict__ x, _Float16* __restrict__ xf) {
    const int gg   = blockIdx.x * 256 + threadIdx.x;
    const int tile = gg >> 6;
    const int lane = gg & 63;
    const int t  = tile >> 8;
    const int rt = (tile >> 4) & 15;
    const int kc = tile & 15;
    const int b  = rt * 16 + (lane & 15);
    const int j0 = kc * 32 + ((lane >> 4) << 3);
    const float* src = x + ((size_t)b * T_ + t) * I_ + j0;
    float4 f0 = *(const float4*)src;
    float4 f1 = *(const float4*)(src + 4);
    half8 h = { (_Float16)f0.x, (_Float16)f0.y, (_Float16)f0.z, (_Float16)f0.w,
                (_Float16)f1.x, (_Float16)f1.y, (_Float16)f1.z, (_Float16)f1.w };
    *(half8*)(xf + (size_t)tile * 512 + lane * 8) = h;
}

// ---------------- small fp32 GEMM ----------------
__global__ __launch_bounds__(256) void small_gemm_kernel(
    const float* __restrict__ A, int lda,
    const float* __restrict__ W, int ldw,
    const float* __restrict__ b1, const float* __restrict__ b2,
    float* __restrict__ out, int N, int K, int relu)
{
    __shared__ float sA2[32][33];
    __shared__ float sW2[32][33];
    int tid = threadIdx.x;
    int tx = tid & 15, ty = tid >> 4;
    int m0 = blockIdx.y * 32, n0 = blockIdx.x * 32;
    float acc[2][2] = {};
    for (int k0 = 0; k0 < K; k0 += 32) {
        __syncthreads();
#pragma unroll
        for (int i = 0; i < 4; ++i) {
            int e = tid + i * 256;
            int r = e >> 5, c = e & 31;
            sA2[r][c] = A[(size_t)(m0 + r) * lda + k0 + c];
            sW2[r][c] = W[(size_t)(n0 + r) * ldw + k0 + c];
        }
        __syncthreads();
#pragma unroll
        for (int k = 0; k < 32; ++k) {
            float a0 = sA2[ty * 2][k], a1 = sA2[ty * 2 + 1][k];
            float w0 = sW2[tx * 2][k], w1 = sW2[tx * 2 + 1][k];
            acc[0][0] += a0 * w0; acc[0][1] += a0 * w1;
            acc[1][0] += a1 * w0; acc[1][1] += a1 * w1;
        }
    }
#pragma unroll
    for (int i = 0; i < 2; ++i)
#pragma unroll
        for (int j = 0; j < 2; ++j) {
            int m = m0 + ty * 2 + i, n = n0 + tx * 2 + j;
            float v = acc[i][j] + b1[n] + (b2 ? b2[n] : 0.0f);
            if (relu) v = fmaxf(v, 0.0f);
            out[(size_t)m * N + n] = v;
        }
}

// ================= PRIMARY encoder: 512 threads, 8 rg x 32 cc =================
// block (rg, cc2): rows rg*32..+31, h-cols cc2*32..+31 (8 n-tiles: n -> gate n>>1,
// col-half n&1). Wave w owns k-chunks kcg = 8*kk + w, kk=0..5 (kk<2: x, else h).
// flags[blk] counts wave drains: block done with step s <=> flags[blk]==8*(s+1).
__global__ __launch_bounds__(512, 1) void enc_w512(
    const _Float16* __restrict__ xf,
    const float* __restrict__ Wih, const float* __restrict__ Whh,
    const float* __restrict__ bih, const float* __restrict__ bhh,
    _Float16* __restrict__ hbuf, float* __restrict__ c_out, int* __restrict__ flags)
{
    const int tid  = threadIdx.x;
    const int wave = tid >> 6, lane = tid & 63;
    const int q = lane >> 4, n15 = lane & 15;
    const int blk = blockIdx.x;
    const int rg  = blk >> 5;    // 0..7
    const int cc2 = blk & 31;    // 0..31

    // weights -> VGPRs (192 regs/lane)
    half8 bw[8][6];
#pragma unroll
    for (int n = 0; n < 8; ++n) {
        const int jc = (n >> 1) * H_ + cc2 * 32 + (n & 1) * 16 + n15;
#pragma unroll
        for (int kk = 0; kk < 6; ++kk) {
            const int k = (8 * kk + wave) * 32 + q * 8;
            const float* src = (k < I_) ? (Wih + (size_t)jc * I_ + k)
                                        : (Whh + (size_t)jc * H_ + (k - I_));
            float4 f0 = *(const float4*)src;
            float4 f1 = *(const float4*)(src + 4);
            bw[n][kk] = half8{(_Float16)f0.x, (_Float16)f0.y, (_Float16)f0.z, (_Float16)f0.w,
                              (_Float16)f1.x, (_Float16)f1.y, (_Float16)f1.z, (_Float16)f1.w};
        }
    }

    // epilogue ownership: thread -> (hcol_l = tid>>4 in 0..31, rowl = tid&15)
    const int hcol_l = tid >> 4;
    const int rowl   = tid & 15;
    float breg[4];
#pragma unroll
    for (int g = 0; g < 4; ++g) {
        const int j = g * H_ + cc2 * 32 + hcol_l;
        breg[g] = bih[j] + bhh[j];
    }
    float creg[2] = {0.f, 0.f};

    // [wave][128 gate-cols][16 rows + pad4]: stride 20 floats (80B, 16B-aligned)
    __shared__ float preT[8][128][20];
    __shared__ unsigned short hsh[32][32];   // h staging [row][col], fp16 bits
    const size_t laneoff = (size_t)lane * 8;

    for (int s = 0; s < T_; ++s) {
        const _Float16* __restrict__ hcur = hbuf + (size_t)(s & 1) * ENC_STEP;
        _Float16* __restrict__ hnxt = hbuf + (size_t)((s + 1) & 1) * ENC_STEP;

        floatx4 acc[2][8];
#pragma unroll
        for (int m = 0; m < 2; ++m)
#pragma unroll
            for (int n = 0; n < 8; ++n) acc[m][n] = floatx4{0.f, 0.f, 0.f, 0.f};

        // ---- x loads + first x-MFMA group (hides producer lag)
        half8 X[2][2];
#pragma unroll
        for (int kk = 0; kk < 2; ++kk)
#pragma unroll
            for (int m = 0; m < 2; ++m)
                X[kk][m] = *(const half8*)(xf + (((size_t)s * 16 + rg * 2 + m) * 16
                                                + (8 * kk + wave)) * 512 + laneoff);
#pragma unroll
        for (int n = 0; n < 8; ++n)
#pragma unroll
            for (int m = 0; m < 2; ++m)
                acc[m][n] = __builtin_amdgcn_mfma_f32_16x16x32_f16(
                    X[0][m], bw[n][0], acc[m][n], 0, 0, 0);

        // ---- wait for h_s: all 32 blocks of rg have all 8 waves drained
        poll_rg(flags, rg * 32, lane & 31, 8 * s);

        // ---- issue all h loads (16 sc1 dwordx2 pairs per lane-equivalent)
        half8 Hb[4][2];
#pragma unroll
        for (int k = 0; k < 4; ++k)
#pragma unroll
            for (int m = 0; m < 2; ++m)
                Hb[k][m] = ldg_h8_sc1(hcur + ((size_t)(rg * 2 + m) * 32
                                              + (8 * k + wave)) * 512 + laneoff);

        // ---- second x-MFMA group covers the first h loads' latency
#pragma unroll
        for (int n = 0; n < 8; ++n)
#pragma unroll
            for (int m = 0; m < 2; ++m)
                acc[m][n] = __builtin_amdgcn_mfma_f32_16x16x32_f16(
                    X[1][m], bw[n][1], acc[m][n], 0, 0, 0);

        // ---- h MFMAs (compiler pipelines waits per Hb[k])
#pragma unroll
        for (int kk = 2; kk < 6; ++kk)
#pragma unroll
            for (int n = 0; n < 8; ++n)
#pragma unroll
                for (int m = 0; m < 2; ++m)
                    acc[m][n] = __builtin_amdgcn_mfma_f32_16x16x32_f16(
                        Hb[kk - 2][m], bw[n][kk], acc[m][n], 0, 0, 0);

        // ---- epilogue: 2 phases (rows m=0: 0..15, m=1: 16..31)
#pragma unroll
        for (int p = 0; p < 2; ++p) {
            if (p) __syncthreads();   // phase-0 reads done before phase-1 writes
#pragma unroll
            for (int n = 0; n < 8; ++n) {
                const int cpre = (n >> 1) * 32 + (n & 1) * 16 + n15;
                *(floatx4*)&preT[wave][cpre][q * 4] = acc[p][n];
            }
            __syncthreads();
            // 8-wave reduce + gates: one h element per thread
            float pg[4];
#pragma unroll
            for (int g = 0; g < 4; ++g) {
                float v = breg[g];
#pragma unroll
                for (int w = 0; w < 8; ++w)
                    v += preT[w][g * 32 + hcol_l][rowl];
                pg[g] = v;
            }
            const float ig = sigmoidf_(pg[0]);
            const float fg = sigmoidf_(pg[1]);
            const float gg = tanhf_(pg[2]);
            const float og = sigmoidf_(pg[3]);
            const float c  = fg * creg[p] + ig * gg;
            creg[p] = c;
            const float hv = og * tanhf_(c);
            union { _Float16 f; unsigned short u; } cv;
            cv.f = (_Float16)hv;
            hsh[p * 16 + rowl][hcol_l] = cv.u;
        }
        __syncthreads();   // all h staged before pack-store

        // ---- pack: one 4B sc1 store per thread in consumer fragment layout
        {
            const int row = tid >> 4;        // 0..31
            const int jp  = tid & 15;        // col-pair 0..15
            const unsigned v = *(const unsigned*)&hsh[row][2 * jp];
            const int lt = (row & 15) | ((jp >> 2) << 4);
            stg_u32_sc1(hnxt + ((size_t)(rg * 2 + (row >> 4)) * 32 + cc2) * 512
                             + lt * 8 + ((2 * jp) & 7), v);
        }

        // ---- barrier-free publication: per-wave drain + count
        wait_vm0();
        if (lane == 0)
            __hip_atomic_fetch_add(&flags[blk], 1, __ATOMIC_RELAXED, __HIP_MEMORY_SCOPE_AGENT);
        __syncthreads();
    }

    // final cell state (plain stores; visible via kernel-end release)
#pragma unroll
    for (int p = 0; p < 2; ++p)
        c_out[(size_t)(rg * 32 + p * 16 + rowl) * H_ + cc2 * 32 + hcol_l] = creg[p];
}

// ================= PRIMARY decoder: dataflow sentinel (round-1/2, measured) =================
__global__ __launch_bounds__(256, 1) void dec_df(
    const float* __restrict__ dWih, const float* __restrict__ dWhh,
    const float* __restrict__ fixedb,
    _Float16* __restrict__ hbuf, float* __restrict__ out)
{
    const int tid  = threadIdx.x;
    const int wave = tid >> 6, lane = tid & 63;
    const int q = lane >> 4, n15 = lane & 15;
    const int blk = blockIdx.x;
    const int rg = blk >> 6, cc = blk & 63;

    half8 bw[2][4];
#pragma unroll
    for (int n = 0; n < 2; ++n) {
        const int jc = (n * 2 + (n15 >> 3)) * I_ + cc * 8 + (n15 & 7);
#pragma unroll
        for (int kc = 0; kc < 4; ++kc) {
            const int k = wave * 128 + kc * 32 + q * 8;
            const float* s0 = dWih + (size_t)jc * (H_ + I_) + H_ + k;
            const float* s1 = dWhh + (size_t)jc * I_ + k;
            float4 a0 = *(const float4*)s0, a1 = *(const float4*)(s0 + 4);
            float4 b0 = *(const float4*)s1, b1 = *(const float4*)(s1 + 4);
            bw[n][kc] = half8{(_Float16)(a0.x + b0.x), (_Float16)(a0.y + b0.y),
                              (_Float16)(a0.z + b0.z), (_Float16)(a0.w + b0.w),
                              (_Float16)(a1.x + b1.x), (_Float16)(a1.y + b1.y),
                              (_Float16)(a1.z + b1.z), (_Float16)(a1.w + b1.w)};
        }
    }

    const int hcp = tid & 3;
    const int rT  = tid >> 2;
    const int brow = rg * 64 + rT;
    float fx[4][2];
#pragma unroll
    for (int g = 0; g < 4; ++g)
#pragma unroll
        for (int e = 0; e < 2; ++e)
            fx[g][e] = fixedb[(size_t)brow * (4 * I_) + g * I_ + cc * 8 + 2 * hcp + e];
    float creg2[2] = {0.f, 0.f};

    __shared__ float preT[4][32][67];
    const size_t laneoff = (size_t)lane * 8;

    for (int s = 0; s < T_; ++s) {
        const _Float16* __restrict__ hcur = hbuf + (size_t)s * DEC_STEP;
        _Float16* __restrict__ hnxt = hbuf + (size_t)(s + 1) * DEC_STEP;

        HU Hb[4][4];
#pragma unroll
        for (int kc = 0; kc < 4; ++kc)
            load_grp<16 * 512>(hcur + ((size_t)(rg * 4) * 16 + (wave * 4 + kc)) * 512
                                    + laneoff, Hb[kc]);

        floatx4 acc[4][2];
#pragma unroll
        for (int m = 0; m < 4; ++m)
#pragma unroll
            for (int n = 0; n < 2; ++n) acc[m][n] = floatx4{0.f, 0.f, 0.f, 0.f};
#pragma unroll
        for (int kc = 0; kc < 4; ++kc) {
            fix_grp<16 * 512>(hcur + ((size_t)(rg * 4) * 16 + (wave * 4 + kc)) * 512
                                   + laneoff, Hb[kc]);
#pragma unroll
            for (int n = 0; n < 2; ++n)
#pragma unroll
                for (int m = 0; m < 4; ++m)
                    acc[m][n] = __builtin_amdgcn_mfma_f32_16x16x32_f16(
                        Hb[kc][m].h, bw[n][kc], acc[m][n], 0, 0, 0);
        }

#pragma unroll
        for (int p = 0; p < 2; ++p) {
            if (p) __syncthreads();
#pragma unroll
            for (int m = 0; m < 2; ++m)
#pragma unroll
                for (int n = 0; n < 2; ++n)
#pragma unroll
                    for (int r = 0; r < 4; ++r)
                        preT[wave][n * 16 + n15][m * 16 + q * 4 + r] = acc[p * 2 + m][n][r];
            __syncthreads();
            if ((rT >> 5) == p) {
                const int rl = rT & 31;
                float pg[4][2];
#pragma unroll
                for (int g = 0; g < 4; ++g)
#pragma unroll
                    for (int e = 0; e < 2; ++e) {
                        const int col = (g >> 1) * 16 + (g & 1) * 8 + 2 * hcp + e;
                        pg[g][e] = preT[0][col][rl] + preT[1][col][rl]
                                 + preT[2][col][rl] + preT[3][col][rl] + fx[g][e];
                    }
                float hv[2];
#pragma unroll
                for (int e = 0; e < 2; ++e) {
                    const float ig = sigmoidf_(pg[0][e]);
                    const float fg = sigmoidf_(pg[1][e]);
                    const float gg = tanhf_(pg[2][e]);
                    const float og = sigmoidf_(pg[3][e]);
                    const float c  = fg * creg2[e] + ig * gg;
                    creg2[e] = c;
                    hv[e] = og * tanhf_(c);
                }
                *(float2*)(out + ((size_t)brow * T_ + (T_ - 1 - s)) * I_ + cc * 8 + 2 * hcp)
                    = float2{hv[0], hv[1]};
                const int j = cc * 8 + 2 * hcp;
                const int kch = j >> 5, j5 = j & 31;
                const int lt  = (rT & 15) | ((j5 >> 3) << 4);
                stg_h2_sc1(hnxt + ((size_t)(rg * 4 + (rT >> 4)) * 16 + kch) * 512
                                + lt * 8 + (j5 & 7), hv[0], hv[1]);
            }
        }
        __syncthreads();
    }
}

// ================= FALLBACK (tiny ws): round-2 verified 256-thread kernels =================
__global__ __launch_bounds__(256, 1) void enc_ring(
    const _Float16* __restrict__ xf,
    const float* __restrict__ Wih, const float* __restrict__ Whh,
    const float* __restrict__ bih, const float* __restrict__ bhh,
    _Float16* __restrict__ hbuf, float* __restrict__ c_out, int* __restrict__ flags)
{
    const int tid  = threadIdx.x;
    const int wave = tid >> 6, lane = tid & 63;
    const int q = lane >> 4, n15 = lane & 15;
    const int blk = blockIdx.x;
    const int rg = blk >> 6, cc = blk & 63;

    half8 bw[4][12];
#pragma unroll
    for (int g = 0; g < 4; ++g) {
        const int jc = g * H_ + cc * 16 + n15;
#pragma unroll
        for (int kc = 0; kc < 12; ++kc) {
            const int k = (4 * kc + wave) * 32 + q * 8;
            const float* src = (k < I_) ? (Wih + (size_t)jc * I_ + k)
                                        : (Whh + (size_t)jc * H_ + (k - I_));
            float4 f0 = *(const float4*)src;
            float4 f1 = *(const float4*)(src + 4);
            bw[g][kc] = half8{(_Float16)f0.x, (_Float16)f0.y, (_Float16)f0.z, (_Float16)f0.w,
                              (_Float16)f1.x, (_Float16)f1.y, (_Float16)f1.z, (_Float16)f1.w};
        }
    }

    const int hcp = tid & 7;
    const int rT  = tid >> 3;
    float breg[4][2];
#pragma unroll
    for (int g = 0; g < 4; ++g)
#pragma unroll
        for (int e = 0; e < 2; ++e) {
            const int j = g * H_ + cc * 16 + 2 * hcp + e;
            breg[g][e] = bih[j] + bhh[j];
        }
    float creg[2][2] = {{0.f, 0.f}, {0.f, 0.f}};

    __shared__ float preT[4][64][35];
    const size_t laneoff = (size_t)lane * 8;

    for (int s = 0; s < T_; ++s) {
        const _Float16* __restrict__ hcur = hbuf + (size_t)(s & 1) * ENC_STEP;
        _Float16* __restrict__ hnxt = hbuf + (size_t)((s + 1) & 1) * ENC_STEP;

        floatx4 acc[4][4];
#pragma unroll
        for (int m = 0; m < 4; ++m)
#pragma unroll
            for (int n = 0; n < 4; ++n) acc[m][n] = floatx4{0.f, 0.f, 0.f, 0.f};

        half8 X[4][4];
#pragma unroll
        for (int kc = 0; kc < 4; ++kc)
#pragma unroll
            for (int m = 0; m < 4; ++m)
                X[kc][m] = *(const half8*)(xf + (((size_t)s * 16 + rg * 4 + m) * 16
                                                + (4 * kc + wave)) * 512 + laneoff);
#pragma unroll
        for (int kc = 0; kc < 4; ++kc)
#pragma unroll
            for (int n = 0; n < 4; ++n)
#pragma unroll
                for (int m = 0; m < 4; ++m)
                    acc[m][n] = __builtin_amdgcn_mfma_f32_16x16x32_f16(
                        X[kc][m], bw[n][kc], acc[m][n], 0, 0, 0);

        poll_rg(flags, rg * 64, lane, 4 * s);

        half8 Hb[4][4];
#pragma unroll
        for (int kc = 4; kc < 8; ++kc)
#pragma unroll
            for (int m = 0; m < 4; ++m)
                Hb[kc - 4][m] = ldg_h8_sc1(hcur + ((size_t)(rg * 4 + m) * 32
                                                   + (4 * kc + wave - 16)) * 512 + laneoff);
#pragma unroll
        for (int kc = 4; kc < 12; ++kc) {
            const int sl = kc & 3;
#pragma unroll
            for (int n = 0; n < 4; ++n)
#pragma unroll
                for (int m = 0; m < 4; ++m)
                    acc[m][n] = __builtin_amdgcn_mfma_f32_16x16x32_f16(
                        Hb[sl][m], bw[n][kc], acc[m][n], 0, 0, 0);
            if (kc < 8) {
#pragma unroll
                for (int m = 0; m < 4; ++m)
                    Hb[sl][m] = ldg_h8_sc1(hcur + ((size_t)(rg * 4 + m) * 32
                                                   + (4 * (kc + 4) + wave - 16)) * 512 + laneoff);
            }
        }

#pragma unroll
        for (int p = 0; p < 2; ++p) {
            if (p) __syncthreads();
#pragma unroll
            for (int m = 0; m < 2; ++m)
#pragma unroll
                for (int n = 0; n < 4; ++n)
#pragma unroll
                    for (int r = 0; r < 4; ++r)
                        preT[wave][n * 16 + n15][m * 16 + q * 4 + r] = acc[p * 2 + m][n][r];
            __syncthreads();
            float pg[4][2];
#pragma unroll
            for (int g = 0; g < 4; ++g)
#pragma unroll
                for (int e = 0; e < 2; ++e) {
                    const int col = g * 16 + 2 * hcp + e;
                    pg[g][e] = preT[0][col][rT] + preT[1][col][rT]
                             + preT[2][col][rT] + preT[3][col][rT] + breg[g][e];
                }
            float hv[2];
#pragma unroll
            for (int e = 0; e < 2; ++e) {
                const float ig = sigmoidf_(pg[0][e]);
                const float fg = sigmoidf_(pg[1][e]);
                const float gg = tanhf_(pg[2][e]);
                const float og = sigmoidf_(pg[3][e]);
                const float c  = fg * creg[p][e] + ig * gg;
                creg[p][e] = c;
                hv[e] = og * tanhf_(c);
            }
            const int row = p * 32 + rT;
            const int j   = cc * 16 + 2 * hcp;
            const int kch = j >> 5, j5 = j & 31;
            const int lt  = (row & 15) | ((j5 >> 3) << 4);
            stg_h2_sc1(hnxt + ((size_t)(rg * 4 + (row >> 4)) * 32 + kch) * 512
                            + lt * 8 + (j5 & 7), hv[0], hv[1]);
        }

        wait_vm0();
        if (lane == 0)
            __hip_atomic_fetch_add(&flags[blk], 1, __ATOMIC_RELAXED, __HIP_MEMORY_SCOPE_AGENT);
        __syncthreads();
    }

#pragma unroll
    for (int p = 0; p < 2; ++p)
        *(float2*)(c_out + (size_t)(rg * 64 + p * 32 + rT) * H_ + cc * 16 + 2 * hcp)
            = float2{creg[p][0], creg[p][1]};
}

__global__ __launch_bounds__(256, 1) void dec_persist(
    const float* __restrict__ dWih, const float* __restrict__ dWhh,
    const float* __restrict__ fixedb,
    _Float16* __restrict__ hbuf, float* __restrict__ out, int* __restrict__ flags)
{
    const int tid  = threadIdx.x;
    const int wave = tid >> 6, lane = tid & 63;
    const int q = lane >> 4, n15 = lane & 15;
    const int blk = blockIdx.x;
    const int rg = blk >> 6, cc = blk & 63;

    half8 bw[2][4];
#pragma unroll
    for (int n = 0; n < 2; ++n) {
        const int jc = (n * 2 + (n15 >> 3)) * I_ + cc * 8 + (n15 & 7);
#pragma unroll
        for (int kc = 0; kc < 4; ++kc) {
            const int k = wave * 128 + kc * 32 + q * 8;
            const float* s0 = dWih + (size_t)jc * (H_ + I_) + H_ + k;
            const float* s1 = dWhh + (size_t)jc * I_ + k;
            float4 a0 = *(const float4*)s0, a1 = *(const float4*)(s0 + 4);
            float4 b0 = *(const float4*)s1, b1 = *(const float4*)(s1 + 4);
            bw[n][kc] = half8{(_Float16)(a0.x + b0.x), (_Float16)(a0.y + b0.y),
                              (_Float16)(a0.z + b0.z), (_Float16)(a0.w + b0.w),
                              (_Float16)(a1.x + b1.x), (_Float16)(a1.y + b1.y),
                              (_Float16)(a1.z + b1.z), (_Float16)(a1.w + b1.w)};
        }
    }

    const int hcp = tid & 3;
    const int rT  = tid >> 2;
    const int brow = rg * 64 + rT;
    float fx[4][2];
#pragma unroll
    for (int g = 0; g < 4; ++g)
#pragma unroll
        for (int e = 0; e < 2; ++e)
            fx[g][e] = fixedb[(size_t)brow * (4 * I_) + g * I_ + cc * 8 + 2 * hcp + e];
    float creg2[2] = {0.f, 0.f};

    __shared__ float preT[4][32][67];
    const size_t laneoff = (size_t)lane * 8;

    for (int s = 0; s < T_; ++s) {
        const _Float16* __restrict__ hcur = hbuf + (size_t)(s & 1) * DEC_STEP;
        _Float16* __restrict__ hnxt = hbuf + (size_t)((s + 1) & 1) * DEC_STEP;

        poll_rg(flags, rg * 64, lane, s);

        half8 Hb[4][4];
#pragma unroll
        for (int kc = 0; kc < 4; ++kc)
#pragma unroll
            for (int m = 0; m < 4; ++m)
                Hb[kc][m] = ldg_h8_sc1(hcur + ((size_t)(rg * 4 + m) * 16
                                               + (wave * 4 + kc)) * 512 + laneoff);
        floatx4 acc[4][2];
#pragma unroll
        for (int m = 0; m < 4; ++m)
#pragma unroll
            for (int n = 0; n < 2; ++n) acc[m][n] = floatx4{0.f, 0.f, 0.f, 0.f};
#pragma unroll
        for (int kc = 0; kc < 4; ++kc)
#pragma unroll
            for (int n = 0; n < 2; ++n)
#pragma unroll
                for (int m = 0; m < 4; ++m)
                    acc[m][n] = __builtin_amdgcn_mfma_f32_16x16x32_f16(
                        Hb[kc][m], bw[n][kc], acc[m][n], 0, 0, 0);

#pragma unroll
        for (int p = 0; p < 2; ++p) {
            if (p) __syncthreads();
#pragma unroll
            for (int m = 0; m < 2; ++m)
#pragma unroll
                for (int n = 0; n < 2; ++n)
#pragma unroll
                    for (int r = 0; r < 4; ++r)
                        preT[wave][n * 16 + n15][m * 16 + q * 4 + r] = acc[p * 2 + m][n][r];
            __syncthreads();
            if ((rT >> 5) == p) {
                const int rl = rT & 31;
                float pg[4][2];
#pragma unroll
                for (int g = 0; g < 4; ++g)
#pragma unroll
                    for (int e = 0; e < 2; ++e) {
                        const int col = (g >> 1) * 16 + (g & 1) * 8 + 2 * hcp + e;
                        pg[g][e] = preT[0][col][rl] + preT[1][col][rl]
                                 + preT[2][col][rl] + preT[3][col][rl] + fx[g][e];
                    }
                float hv[2];
#pragma unroll
                for (int e = 0; e < 2; ++e) {
                    const float ig = sigmoidf_(pg[0][e]);
                    const float fg = sigmoidf_(pg[1][e]);
                    const float gg = tanhf_(pg[2][e]);
                    const float og = sigmoidf_(pg[3][e]);
                    const float c  = fg * creg2[e] + ig * gg;
                    creg2[e] = c;
                    hv[e] = og * tanhf_(c);
                }
                *(float2*)(out + ((size_t)brow * T_ + (T_ - 1 - s)) * I_ + cc * 8 + 2 * hcp)
                    = float2{hv[0], hv[1]};
                const int j = cc * 8 + 2 * hcp;
                const int kch = j >> 5, j5 = j & 31;
                const int lt  = (rT & 15) | ((j5 >> 3) << 4);
                stg_h2_sc1(hnxt + ((size_t)(rg * 4 + (rT >> 4)) * 16 + kch) * 512
                                + lt * 8 + (j5 & 7), hv[0], hv[1]);
            }
        }

        wait_vm0();
        __syncthreads();
        if (tid == 0)
            __hip_atomic_store(&flags[blk], s + 1, __ATOMIC_RELAXED, __HIP_MEMORY_SCOPE_AGENT);
    }
}

// ---------------- launch ----------------
extern "C" void kernel_launch(void* const* d_in, const int* in_sizes, int n_in,
                              void* d_out_v, int out_size, void* d_ws, size_t ws_size,
                              hipStream_t stream) {
    (void)in_sizes; (void)n_in; (void)out_size;
    const float* x    = (const float*)d_in[0];
    const float* eWih = (const float*)d_in[1];
    const float* eWhh = (const float*)d_in[2];
    const float* ebih = (const float*)d_in[3];
    const float* ebhh = (const float*)d_in[4];
    const float* efcW = (const float*)d_in[5];
    const float* efcb = (const float*)d_in[6];
    const float* dfcW = (const float*)d_in[7];
    const float* dfcb = (const float*)d_in[8];
    const float* dWih = (const float*)d_in[9];
    const float* dWhh = (const float*)d_in[10];
    const float* dbih = (const float*)d_in[11];
    const float* dbhh = (const float*)d_in[12];
    float* d_out = (float*)d_out_v;

    char* ws = (char*)d_ws;
    size_t off = 0;
    auto carve = [&](size_t bytes) {
        char* p = ws + off;
        off += (bytes + 255) & ~(size_t)255;
        return p;
    };

    const size_t xf_b  = (size_t)B_ * T_ * I_ * 2;
    const size_t hbE_b = (size_t)2 * ENC_STEP * 2;          // 2-slot ring
    const size_t hbD_b = (size_t)(T_ + 1) * DEC_STEP * 2;   // 129 unique slots
    const size_t ce_b  = (size_t)B_ * H_ * 4;
    const size_t fxb_b = (size_t)B_ * 4 * I_ * 4;
    const size_t d1_b  = (size_t)B_ * H_ * 4;
    const size_t need_primary = xf_b + hbE_b + hbD_b + ce_b + fxb_b + d1_b + 8192;

    float* embd = d_out + (size_t)B_ * T_ * I_;

    if (ws_size == 0 || ws_size >= need_primary) {
        // ---------- primary: 512-thread encoder + dataflow decoder ----------
        _Float16* xf     = (_Float16*)carve(xf_b);
        _Float16* hbufE  = (_Float16*)carve(hbE_b);
        _Float16* hbufD  = (_Float16*)carve(hbD_b);
        float*    c_e    = (float*)carve(ce_b);
        float*    fixedb = (float*)carve(fxb_b);
        float*    dec1   = (float*)carve(d1_b);
        int*      flagsE = (int*)carve(256 * 4);

        hipMemsetAsync(flagsE, 0, 256 * 4, stream);
        hipMemsetAsync(hbufE, 0, (size_t)ENC_STEP * 2, stream);  // h0 = 0 (slot 0)
        // decoder: slot 0 = h0 = 0; slots 1..T poisoned with fp16 NaN
        hipMemsetAsync(hbufD, 0, (size_t)DEC_STEP * 2, stream);
        hipMemsetAsync((char*)hbufD + (size_t)DEC_STEP * 2, 0x7C, (size_t)T_ * DEC_STEP * 2, stream);

        shuffle_x_kernel<<<dim3(8192), 256, 0, stream>>>(x, xf);
        enc_w512<<<dim3(256), 512, 0, stream>>>(xf, eWih, eWhh, ebih, ebhh,
                                                hbufE, c_e, flagsE);
        small_gemm_kernel<<<dim3(E_ / 32, B_ / 32), 256, 0, stream>>>(
            c_e, H_, efcW, H_, efcb, nullptr, embd, E_, H_, 1);
        small_gemm_kernel<<<dim3(H_ / 32, B_ / 32), 256, 0, stream>>>(
            embd, E_, dfcW, E_, dfcb, nullptr, dec1, H_, E_, 1);
        small_gemm_kernel<<<dim3(4 * I_ / 32, B_ / 32), 256, 0, stream>>>(
            dec1, H_, dWih, H_ + I_, dbih, dbhh, fixedb, 4 * I_, H_, 0);
        dec_df<<<dim3(256), 256, 0, stream>>>(dWih, dWhh, fixedb, hbufD, d_out);
    } else {
        // ---------- fallback: 2-slot-ring flag protocol (round-2 verified) ----------
        _Float16* xf     = (_Float16*)carve(xf_b);
        _Float16* hbufE  = (_Float16*)carve((size_t)2 * ENC_STEP * 2);
        _Float16* hbufD  = (_Float16*)carve((size_t)2 * DEC_STEP * 2);
        float*    c_e    = (float*)carve(ce_b);
        float*    fixedb = (float*)carve(fxb_b);
        float*    dec1   = (float*)carve(d1_b);
        int*      flagsE = (int*)carve(256 * 4);
        int*      flagsD = (int*)carve(256 * 4);

        hipMemsetAsync(flagsE, 0, 256 * 4, stream);
        hipMemsetAsync(flagsD, 0, 256 * 4, stream);
        hipMemsetAsync(hbufE, 0, (size_t)ENC_STEP * 2, stream);
        hipMemsetAsync(hbufD, 0, (size_t)DEC_STEP * 2, stream);

        shuffle_x_kernel<<<dim3(8192), 256, 0, stream>>>(x, xf);
        enc_ring<<<dim3(256), 256, 0, stream>>>(xf, eWih, eWhh, ebih, ebhh,
                                                hbufE, c_e, flagsE);
        small_gemm_kernel<<<dim3(E_ / 32, B_ / 32), 256, 0, stream>>>(
            c_e, H_, efcW, H_, efcb, nullptr, embd, E_, H_, 1);
        small_gemm_kernel<<<dim3(H_ / 32, B_ / 32), 256, 0, stream>>>(
            embd, E_, dfcW, E_, dfcb, nullptr, dec1, H_, E_, 1);
        small_gemm_kernel<<<dim3(4 * I_ / 32, B_ / 32), 256, 0, stream>>>(
            dec1, H_, dWih, H_ + I_, dbih, dbhh, fixedb, 4 * I_, H_, 0);
        dec_persist<<<dim3(256), 256, 0, stream>>>(dWih, dWhh, fixedb,
                                                   hbufD, d_out, flagsD);
    }
}

// Round 5
// 2285.845 us; speedup vs baseline: 1.4909x; 1.4909x over previous
//
#include <hip/hip_runtime.h>
#include <hip/hip_fp16.h>

// LSTM Autoencoder: B=256, T=128, I=512, H=1024, E=256
// Round-7: revert to round-2 proven pair; remove x-work + one sync phase from
// the encoder's serial chain.
//  - enc_xp (4rg x 64cc, 256thr, flag protocol, 2-slot ring -- round-2 core):
//    (a) next-step X prefetched during h-MFMA phase; x-MFMAs deferred to after
//        the preT writes (acc dead -> rezeroed), overlapping the epilogue's
//        VALU on the separate matrix pipe. x leaves the inter-block chain.
//    (b) single-phase epilogue: preT[4][64][67] (68.6 KB LDS), one barrier
//        round-trip instead of two.
//  - dec_df: byte-identical round-1/2/4 dataflow sentinel kernel (~630us).
//  - Round-4 spill lesson: watch VGPR_Count (~400 expected, spill if <=256).

#define B_ 256
#define T_ 128
#define I_ 512
#define H_ 1024
#define E_ 256

#define ENC_STEP 262144   // fp16 elems per encoder h slot (256x1024)
#define DEC_STEP 131072   // fp16 elems per decoder h slot (256x512)
#define SENT32 0x7C7C7C7Cu   // two fp16 NaNs; unreachable by real h pairs

typedef _Float16 half8 __attribute__((ext_vector_type(8)));
typedef float floatx4 __attribute__((ext_vector_type(4)));

__device__ __forceinline__ float sigmoidf_(float x) { return 1.0f / (1.0f + __expf(-x)); }
__device__ __forceinline__ float tanhf_(float x) {
    x = fminf(fmaxf(x, -15.0f), 15.0f);
    float e = __expf(2.0f * x);
    return (e - 1.0f) / (e + 1.0f);
}

union HU { unsigned long long u[2]; unsigned v[4]; half8 h; };

// coherent 16B load as 2x u64 relaxed-agent atomics (global_load_dwordx2 sc0 sc1)
__device__ __forceinline__ void ld_chunk(const _Float16* p, HU& v) {
    const unsigned long long* q = (const unsigned long long*)p;
    v.u[0] = __hip_atomic_load(q,     __ATOMIC_RELAXED, __HIP_MEMORY_SCOPE_AGENT);
    v.u[1] = __hip_atomic_load(q + 1, __ATOMIC_RELAXED, __HIP_MEMORY_SCOPE_AGENT);
}
__device__ __forceinline__ int chunk_ok(const HU& v) {
    return (int)((v.v[0] != SENT32) & (v.v[1] != SENT32)
               & (v.v[2] != SENT32) & (v.v[3] != SENT32));
}
template <int STRIDE>
__device__ __forceinline__ void load_grp(const _Float16* base, HU v[4]) {
#pragma unroll
    for (int m = 0; m < 4; ++m) ld_chunk(base + (size_t)m * STRIDE, v[m]);
}
template <int STRIDE>
__device__ __forceinline__ void fix_grp(const _Float16* base, HU v[4]) {
    while (!(chunk_ok(v[0]) & chunk_ok(v[1]) & chunk_ok(v[2]) & chunk_ok(v[3]))) {
        __builtin_amdgcn_s_sleep(1);
        load_grp<STRIDE>(base, v);
    }
}

__device__ __forceinline__ half8 ldg_h8_sc1(const _Float16* p) {
    HU v; ld_chunk(p, v); return v.h;
}
__device__ __forceinline__ void stg_h2_sc1(_Float16* p, float a, float b) {
    union { _Float16 h[2]; unsigned int u; } v;
    v.h[0] = (_Float16)a; v.h[1] = (_Float16)b;
    __hip_atomic_store((unsigned int*)p, v.u, __ATOMIC_RELAXED, __HIP_MEMORY_SCOPE_AGENT);
}
__device__ __forceinline__ void wait_vm0() {
    asm volatile("s_waitcnt vmcnt(0)" ::: "memory");
}
__device__ __forceinline__ void poll_rg(int* flags, int rgbase, int lane, int target) {
    while (__hip_atomic_load(&flags[rgbase + lane], __ATOMIC_RELAXED, __HIP_MEMORY_SCOPE_AGENT) < target)
        __builtin_amdgcn_s_sleep(1);
    asm volatile("" ::: "memory");
}

// ---------------- x -> MFMA A-fragment layout (once) ----------------
__global__ void shuffle_x_kernel(const float* __restrict__ x, _Float16* __restrict__ xf) {
    const int gg   = blockIdx.x * 256 + threadIdx.x;
    const int tile = gg >> 6;
    const int lane = gg & 63;
    const int t  = tile >> 8;
    const int rt = (tile >> 4) & 15;
    const int kc = tile & 15;
    const int b  = rt * 16 + (lane & 15);
    const int j0 = kc * 32 + ((lane >> 4) << 3);
    const float* src = x + ((size_t)b * T_ + t) * I_ + j0;
    float4 f0 = *(const float4*)src;
    float4 f1 = *(const float4*)(src + 4);
    half8 h = { (_Float16)f0.x, (_Float16)f0.y, (_Float16)f0.z, (_Float16)f0.w,
                (_Float16)f1.x, (_Float16)f1.y, (_Float16)f1.z, (_Float16)f1.w };
    *(half8*)(xf + (size_t)tile * 512 + lane * 8) = h;
}

// ---------------- small fp32 GEMM ----------------
__global__ __launch_bounds__(256) void small_gemm_kernel(
    const float* __restrict__ A, int lda,
    const float* __restrict__ W, int ldw,
    const float* __restrict__ b1, const float* __restrict__ b2,
    float* __restrict__ out, int N, int K, int relu)
{
    __shared__ float sA2[32][33];
    __shared__ float sW2[32][33];
    int tid = threadIdx.x;
    int tx = tid & 15, ty = tid >> 4;
    int m0 = blockIdx.y * 32, n0 = blockIdx.x * 32;
    float acc[2][2] = {};
    for (int k0 = 0; k0 < K; k0 += 32) {
        __syncthreads();
#pragma unroll
        for (int i = 0; i < 4; ++i) {
            int e = tid + i * 256;
            int r = e >> 5, c = e & 31;
            sA2[r][c] = A[(size_t)(m0 + r) * lda + k0 + c];
            sW2[r][c] = W[(size_t)(n0 + r) * ldw + k0 + c];
        }
        __syncthreads();
#pragma unroll
        for (int k = 0; k < 32; ++k) {
            float a0 = sA2[ty * 2][k], a1 = sA2[ty * 2 + 1][k];
            float w0 = sW2[tx * 2][k], w1 = sW2[tx * 2 + 1][k];
            acc[0][0] += a0 * w0; acc[0][1] += a0 * w1;
            acc[1][0] += a1 * w0; acc[1][1] += a1 * w1;
        }
    }
#pragma unroll
    for (int i = 0; i < 2; ++i)
#pragma unroll
        for (int j = 0; j < 2; ++j) {
            int m = m0 + ty * 2 + i, n = n0 + tx * 2 + j;
            float v = acc[i][j] + b1[n] + (b2 ? b2[n] : 0.0f);
            if (relu) v = fmaxf(v, 0.0f);
            out[(size_t)m * N + n] = v;
        }
}

// ================= PRIMARY encoder: x-deferred, single-phase epilogue =================
// grid 256 = 4 row-groups (64 batch rows) x 64 col-CUs (16 h-cols -> 64 gate-cols)
// flags[blk] counts wave drains: block done with step s <=> flags[blk]==4*(s+1).
__global__ __launch_bounds__(256, 1) void enc_xp(
    const _Float16* __restrict__ xf,
    const float* __restrict__ Wih, const float* __restrict__ Whh,
    const float* __restrict__ bih, const float* __restrict__ bhh,
    _Float16* __restrict__ hbuf, float* __restrict__ c_out, int* __restrict__ flags)
{
    const int tid  = threadIdx.x;
    const int wave = tid >> 6, lane = tid & 63;
    const int q = lane >> 4, n15 = lane & 15;
    const int blk = blockIdx.x;
    const int rg = blk >> 6, cc = blk & 63;

    // weights -> VGPRs (192 regs/lane)
    half8 bw[4][12];
#pragma unroll
    for (int g = 0; g < 4; ++g) {
        const int jc = g * H_ + cc * 16 + n15;
#pragma unroll
        for (int kc = 0; kc < 12; ++kc) {
            const int k = (4 * kc + wave) * 32 + q * 8;
            const float* src = (k < I_) ? (Wih + (size_t)jc * I_ + k)
                                        : (Whh + (size_t)jc * H_ + (k - I_));
            float4 f0 = *(const float4*)src;
            float4 f1 = *(const float4*)(src + 4);
            bw[g][kc] = half8{(_Float16)f0.x, (_Float16)f0.y, (_Float16)f0.z, (_Float16)f0.w,
                              (_Float16)f1.x, (_Float16)f1.y, (_Float16)f1.z, (_Float16)f1.w};
        }
    }

    const int hcp = tid & 7;    // owned col-pair (2*hcp, 2*hcp+1)
    const int rT  = tid >> 3;   // owned rows rT (p=0), 32+rT (p=1)
    float breg[4][2];
#pragma unroll
    for (int g = 0; g < 4; ++g)
#pragma unroll
        for (int e = 0; e < 2; ++e) {
            const int j = g * H_ + cc * 16 + 2 * hcp + e;
            breg[g][e] = bih[j] + bhh[j];
        }
    float creg[2][2] = {{0.f, 0.f}, {0.f, 0.f}};

    // single-phase transpose buffer: [wave][64 gate-cols][64 rows + pad3]
    __shared__ float preT[4][64][67];   // 68.6 KB
    const size_t laneoff = (size_t)lane * 8;

    // ---- prologue: X(s=0) + x-MFMAs into acc
    floatx4 acc[4][4];
#pragma unroll
    for (int m = 0; m < 4; ++m)
#pragma unroll
        for (int n = 0; n < 4; ++n) acc[m][n] = floatx4{0.f, 0.f, 0.f, 0.f};
    half8 X[4][4];
#pragma unroll
    for (int kc = 0; kc < 4; ++kc)
#pragma unroll
        for (int m = 0; m < 4; ++m)
            X[kc][m] = *(const half8*)(xf + (((size_t)0 * 16 + rg * 4 + m) * 16
                                            + (4 * kc + wave)) * 512 + laneoff);
#pragma unroll
    for (int kc = 0; kc < 4; ++kc)
#pragma unroll
        for (int n = 0; n < 4; ++n)
#pragma unroll
            for (int m = 0; m < 4; ++m)
                acc[m][n] = __builtin_amdgcn_mfma_f32_16x16x32_f16(
                    X[kc][m], bw[n][kc], acc[m][n], 0, 0, 0);

    for (int s = 0; s < T_; ++s) {
        const _Float16* __restrict__ hcur = hbuf + (size_t)(s & 1) * ENC_STEP;
        _Float16* __restrict__ hnxt = hbuf + (size_t)((s + 1) & 1) * ENC_STEP;

        // ---- wait for h_s: all 64 blocks of rg have all 4 waves drained
        poll_rg(flags, rg * 64, lane, 4 * s);

        // ---- issue first 4 h-load groups
        half8 Hb[4][4];
#pragma unroll
        for (int kc = 4; kc < 8; ++kc)
#pragma unroll
            for (int m = 0; m < 4; ++m)
                Hb[kc - 4][m] = ldg_h8_sc1(hcur + ((size_t)(rg * 4 + m) * 32
                                                   + (4 * kc + wave - 16)) * 512 + laneoff);

        // ---- prefetch X(s+1): latency hidden under h-MFMA phase
        if (s + 1 < T_) {
#pragma unroll
            for (int kc = 0; kc < 4; ++kc)
#pragma unroll
                for (int m = 0; m < 4; ++m)
                    X[kc][m] = *(const half8*)(xf + (((size_t)(s + 1) * 16 + rg * 4 + m) * 16
                                                    + (4 * kc + wave)) * 512 + laneoff);
        }

        // ---- h phase: depth-4 pipelined sc1 loads + 128 MFMAs
#pragma unroll
        for (int kc = 4; kc < 12; ++kc) {
            const int sl = kc & 3;
#pragma unroll
            for (int n = 0; n < 4; ++n)
#pragma unroll
                for (int m = 0; m < 4; ++m)
                    acc[m][n] = __builtin_amdgcn_mfma_f32_16x16x32_f16(
                        Hb[sl][m], bw[n][kc], acc[m][n], 0, 0, 0);
            if (kc < 8) {
#pragma unroll
                for (int m = 0; m < 4; ++m)
                    Hb[sl][m] = ldg_h8_sc1(hcur + ((size_t)(rg * 4 + m) * 32
                                                   + (4 * (kc + 4) + wave - 16)) * 512 + laneoff);
            }
        }

        // ---- single-phase epilogue: dump all 64 rows, one barrier
#pragma unroll
        for (int m = 0; m < 4; ++m)
#pragma unroll
            for (int n = 0; n < 4; ++n)
#pragma unroll
                for (int r = 0; r < 4; ++r)
                    preT[wave][n * 16 + n15][m * 16 + q * 4 + r] = acc[m][n][r];
        __syncthreads();

        // ---- acc is dead: rezero + deferred x-MFMAs for s+1 (matrix pipe),
        //      overlapping the reduce/gates VALU below
#pragma unroll
        for (int m = 0; m < 4; ++m)
#pragma unroll
            for (int n = 0; n < 4; ++n) acc[m][n] = floatx4{0.f, 0.f, 0.f, 0.f};
        if (s + 1 < T_) {
#pragma unroll
            for (int kc = 0; kc < 4; ++kc)
#pragma unroll
                for (int n = 0; n < 4; ++n)
#pragma unroll
                    for (int m = 0; m < 4; ++m)
                        acc[m][n] = __builtin_amdgcn_mfma_f32_16x16x32_f16(
                            X[kc][m], bw[n][kc], acc[m][n], 0, 0, 0);
        }

        // ---- reduce + gates + h stores (both row halves)
#pragma unroll
        for (int p = 0; p < 2; ++p) {
            const int row = p * 32 + rT;
            float pg[4][2];
#pragma unroll
            for (int g = 0; g < 4; ++g)
#pragma unroll
                for (int e = 0; e < 2; ++e) {
                    const int col = g * 16 + 2 * hcp + e;
                    pg[g][e] = preT[0][col][row] + preT[1][col][row]
                             + preT[2][col][row] + preT[3][col][row] + breg[g][e];
                }
            float hv[2];
#pragma unroll
            for (int e = 0; e < 2; ++e) {
                const float ig = sigmoidf_(pg[0][e]);
                const float fg = sigmoidf_(pg[1][e]);
                const float gg = tanhf_(pg[2][e]);
                const float og = sigmoidf_(pg[3][e]);
                const float c  = fg * creg[p][e] + ig * gg;
                creg[p][e] = c;
                hv[e] = og * tanhf_(c);
            }
            const int j   = cc * 16 + 2 * hcp;
            const int kch = j >> 5, j5 = j & 31;
            const int lt  = (row & 15) | ((j5 >> 3) << 4);
            stg_h2_sc1(hnxt + ((size_t)(rg * 4 + (row >> 4)) * 32 + kch) * 512
                            + lt * 8 + (j5 & 7), hv[0], hv[1]);
        }

        // ---- barrier-free publication: per-wave drain + count
        wait_vm0();
        if (lane == 0)
            __hip_atomic_fetch_add(&flags[blk], 1, __ATOMIC_RELAXED, __HIP_MEMORY_SCOPE_AGENT);
        __syncthreads();     // preT reuse protection (off the inter-block path)
    }

    // final cell state (plain stores; visible via kernel-end release)
#pragma unroll
    for (int p = 0; p < 2; ++p)
        *(float2*)(c_out + (size_t)(rg * 64 + p * 32 + rT) * H_ + cc * 16 + 2 * hcp)
            = float2{creg[p][0], creg[p][1]};
}

// ================= PRIMARY decoder: dataflow sentinel (measured, unchanged) =================
__global__ __launch_bounds__(256, 1) void dec_df(
    const float* __restrict__ dWih, const float* __restrict__ dWhh,
    const float* __restrict__ fixedb,
    _Float16* __restrict__ hbuf, float* __restrict__ out)
{
    const int tid  = threadIdx.x;
    const int wave = tid >> 6, lane = tid & 63;
    const int q = lane >> 4, n15 = lane & 15;
    const int blk = blockIdx.x;
    const int rg = blk >> 6, cc = blk & 63;

    half8 bw[2][4];
#pragma unroll
    for (int n = 0; n < 2; ++n) {
        const int jc = (n * 2 + (n15 >> 3)) * I_ + cc * 8 + (n15 & 7);
#pragma unroll
        for (int kc = 0; kc < 4; ++kc) {
            const int k = wave * 128 + kc * 32 + q * 8;
            const float* s0 = dWih + (size_t)jc * (H_ + I_) + H_ + k;
            const float* s1 = dWhh + (size_t)jc * I_ + k;
            float4 a0 = *(const float4*)s0, a1 = *(const float4*)(s0 + 4);
            float4 b0 = *(const float4*)s1, b1 = *(const float4*)(s1 + 4);
            bw[n][kc] = half8{(_Float16)(a0.x + b0.x), (_Float16)(a0.y + b0.y),
                              (_Float16)(a0.z + b0.z), (_Float16)(a0.w + b0.w),
                              (_Float16)(a1.x + b1.x), (_Float16)(a1.y + b1.y),
                              (_Float16)(a1.z + b1.z), (_Float16)(a1.w + b1.w)};
        }
    }

    const int hcp = tid & 3;
    const int rT  = tid >> 2;
    const int brow = rg * 64 + rT;
    float fx[4][2];
#pragma unroll
    for (int g = 0; g < 4; ++g)
#pragma unroll
        for (int e = 0; e < 2; ++e)
            fx[g][e] = fixedb[(size_t)brow * (4 * I_) + g * I_ + cc * 8 + 2 * hcp + e];
    float creg2[2] = {0.f, 0.f};

    __shared__ float preT[4][32][67];
    const size_t laneoff = (size_t)lane * 8;

    for (int s = 0; s < T_; ++s) {
        const _Float16* __restrict__ hcur = hbuf + (size_t)s * DEC_STEP;
        _Float16* __restrict__ hnxt = hbuf + (size_t)(s + 1) * DEC_STEP;

        HU Hb[4][4];
#pragma unroll
        for (int kc = 0; kc < 4; ++kc)
            load_grp<16 * 512>(hcur + ((size_t)(rg * 4) * 16 + (wave * 4 + kc)) * 512
                                    + laneoff, Hb[kc]);

        floatx4 acc[4][2];
#pragma unroll
        for (int m = 0; m < 4; ++m)
#pragma unroll
            for (int n = 0; n < 2; ++n) acc[m][n] = floatx4{0.f, 0.f, 0.f, 0.f};
#pragma unroll
        for (int kc = 0; kc < 4; ++kc) {
            fix_grp<16 * 512>(hcur + ((size_t)(rg * 4) * 16 + (wave * 4 + kc)) * 512
                                   + laneoff, Hb[kc]);
#pragma unroll
            for (int n = 0; n < 2; ++n)
#pragma unroll
                for (int m = 0; m < 4; ++m)
                    acc[m][n] = __builtin_amdgcn_mfma_f32_16x16x32_f16(
                        Hb[kc][m].h, bw[n][kc], acc[m][n], 0, 0, 0);
        }

#pragma unroll
        for (int p = 0; p < 2; ++p) {
            if (p) __syncthreads();
#pragma unroll
            for (int m = 0; m < 2; ++m)
#pragma unroll
                for (int n = 0; n < 2; ++n)
#pragma unroll
                    for (int r = 0; r < 4; ++r)
                        preT[wave][n * 16 + n15][m * 16 + q * 4 + r] = acc[p * 2 + m][n][r];
            __syncthreads();
            if ((rT >> 5) == p) {
                const int rl = rT & 31;
                float pg[4][2];
#pragma unroll
                for (int g = 0; g < 4; ++g)
#pragma unroll
                    for (int e = 0; e < 2; ++e) {
                        const int col = (g >> 1) * 16 + (g & 1) * 8 + 2 * hcp + e;
                        pg[g][e] = preT[0][col][rl] + preT[1][col][rl]
                                 + preT[2][col][rl] + preT[3][col][rl] + fx[g][e];
                    }
                float hv[2];
#pragma unroll
                for (int e = 0; e < 2; ++e) {
                    const float ig = sigmoidf_(pg[0][e]);
                    const float fg = sigmoidf_(pg[1][e]);
                    const float gg = tanhf_(pg[2][e]);
                    const float og = sigmoidf_(pg[3][e]);
                    const float c  = fg * creg2[e] + ig * gg;
                    creg2[e] = c;
                    hv[e] = og * tanhf_(c);
                }
                *(float2*)(out + ((size_t)brow * T_ + (T_ - 1 - s)) * I_ + cc * 8 + 2 * hcp)
                    = float2{hv[0], hv[1]};
                const int j = cc * 8 + 2 * hcp;
                const int kch = j >> 5, j5 = j & 31;
                const int lt  = (rT & 15) | ((j5 >> 3) << 4);
                stg_h2_sc1(hnxt + ((size_t)(rg * 4 + (rT >> 4)) * 16 + kch) * 512
                                + lt * 8 + (j5 & 7), hv[0], hv[1]);
            }
        }
        __syncthreads();
    }
}

// ================= FALLBACK (tiny ws): round-2 verified kernels =================
__global__ __launch_bounds__(256, 1) void enc_ring(
    const _Float16* __restrict__ xf,
    const float* __restrict__ Wih, const float* __restrict__ Whh,
    const float* __restrict__ bih, const float* __restrict__ bhh,
    _Float16* __restrict__ hbuf, float* __restrict__ c_out, int* __restrict__ flags)
{
    const int tid  = threadIdx.x;
    const int wave = tid >> 6, lane = tid & 63;
    const int q = lane >> 4, n15 = lane & 15;
    const int blk = blockIdx.x;
    const int rg = blk >> 6, cc = blk & 63;

    half8 bw[4][12];
#pragma unroll
    for (int g = 0; g < 4; ++g) {
        const int jc = g * H_ + cc * 16 + n15;
#pragma unroll
        for (int kc = 0; kc < 12; ++kc) {
            const int k = (4 * kc + wave) * 32 + q * 8;
            const float* src = (k < I_) ? (Wih + (size_t)jc * I_ + k)
                                        : (Whh + (size_t)jc * H_ + (k - I_));
            float4 f0 = *(const float4*)src;
            float4 f1 = *(const float4*)(src + 4);
            bw[g][kc] = half8{(_Float16)f0.x, (_Float16)f0.y, (_Float16)f0.z, (_Float16)f0.w,
                              (_Float16)f1.x, (_Float16)f1.y, (_Float16)f1.z, (_Float16)f1.w};
        }
    }

    const int hcp = tid & 7;
    const int rT  = tid >> 3;
    float breg[4][2];
#pragma unroll
    for (int g = 0; g < 4; ++g)
#pragma unroll
        for (int e = 0; e < 2; ++e) {
            const int j = g * H_ + cc * 16 + 2 * hcp + e;
            breg[g][e] = bih[j] + bhh[j];
        }
    float creg[2][2] = {{0.f, 0.f}, {0.f, 0.f}};

    __shared__ float preT[4][64][35];
    const size_t laneoff = (size_t)lane * 8;

    for (int s = 0; s < T_; ++s) {
        const _Float16* __restrict__ hcur = hbuf + (size_t)(s & 1) * ENC_STEP;
        _Float16* __restrict__ hnxt = hbuf + (size_t)((s + 1) & 1) * ENC_STEP;

        floatx4 acc[4][4];
#pragma unroll
        for (int m = 0; m < 4; ++m)
#pragma unroll
            for (int n = 0; n < 4; ++n) acc[m][n] = floatx4{0.f, 0.f, 0.f, 0.f};

        half8 X[4][4];
#pragma unroll
        for (int kc = 0; kc < 4; ++kc)
#pragma unroll
            for (int m = 0; m < 4; ++m)
                X[kc][m] = *(const half8*)(xf + (((size_t)s * 16 + rg * 4 + m) * 16
                                                + (4 * kc + wave)) * 512 + laneoff);
#pragma unroll
        for (int kc = 0; kc < 4; ++kc)
#pragma unroll
            for (int n = 0; n < 4; ++n)
#pragma unroll
                for (int m = 0; m < 4; ++m)
                    acc[m][n] = __builtin_amdgcn_mfma_f32_16x16x32_f16(
                        X[kc][m], bw[n][kc], acc[m][n], 0, 0, 0);

        poll_rg(flags, rg * 64, lane, 4 * s);

        half8 Hb[4][4];
#pragma unroll
        for (int kc = 4; kc < 8; ++kc)
#pragma unroll
            for (int m = 0; m < 4; ++m)
                Hb[kc - 4][m] = ldg_h8_sc1(hcur + ((size_t)(rg * 4 + m) * 32
                                                   + (4 * kc + wave - 16)) * 512 + laneoff);
#pragma unroll
        for (int kc = 4; kc < 12; ++kc) {
            const int sl = kc & 3;
#pragma unroll
            for (int n = 0; n < 4; ++n)
#pragma unroll
                for (int m = 0; m < 4; ++m)
                    acc[m][n] = __builtin_amdgcn_mfma_f32_16x16x32_f16(
                        Hb[sl][m], bw[n][kc], acc[m][n], 0, 0, 0);
            if (kc < 8) {
#pragma unroll
                for (int m = 0; m < 4; ++m)
                    Hb[sl][m] = ldg_h8_sc1(hcur + ((size_t)(rg * 4 + m) * 32
                                                   + (4 * (kc + 4) + wave - 16)) * 512 + laneoff);
            }
        }

#pragma unroll
        for (int p = 0; p < 2; ++p) {
            if (p) __syncthreads();
#pragma unroll
            for (int m = 0; m < 2; ++m)
#pragma unroll
                for (int n = 0; n < 4; ++n)
#pragma unroll
                    for (int r = 0; r < 4; ++r)
                        preT[wave][n * 16 + n15][m * 16 + q * 4 + r] = acc[p * 2 + m][n][r];
            __syncthreads();
            float pg[4][2];
#pragma unroll
            for (int g = 0; g < 4; ++g)
#pragma unroll
                for (int e = 0; e < 2; ++e) {
                    const int col = g * 16 + 2 * hcp + e;
                    pg[g][e] = preT[0][col][rT] + preT[1][col][rT]
                             + preT[2][col][rT] + preT[3][col][rT] + breg[g][e];
                }
            float hv[2];
#pragma unroll
            for (int e = 0; e < 2; ++e) {
                const float ig = sigmoidf_(pg[0][e]);
                const float fg = sigmoidf_(pg[1][e]);
                const float gg = tanhf_(pg[2][e]);
                const float og = sigmoidf_(pg[3][e]);
                const float c  = fg * creg[p][e] + ig * gg;
                creg[p][e] = c;
                hv[e] = og * tanhf_(c);
            }
            const int row = p * 32 + rT;
            const int j   = cc * 16 + 2 * hcp;
            const int kch = j >> 5, j5 = j & 31;
            const int lt  = (row & 15) | ((j5 >> 3) << 4);
            stg_h2_sc1(hnxt + ((size_t)(rg * 4 + (row >> 4)) * 32 + kch) * 512
                            + lt * 8 + (j5 & 7), hv[0], hv[1]);
        }

        wait_vm0();
        if (lane == 0)
            __hip_atomic_fetch_add(&flags[blk], 1, __ATOMIC_RELAXED, __HIP_MEMORY_SCOPE_AGENT);
        __syncthreads();
    }

#pragma unroll
    for (int p = 0; p < 2; ++p)
        *(float2*)(c_out + (size_t)(rg * 64 + p * 32 + rT) * H_ + cc * 16 + 2 * hcp)
            = float2{creg[p][0], creg[p][1]};
}

__global__ __launch_bounds__(256, 1) void dec_persist(
    const float* __restrict__ dWih, const float* __restrict__ dWhh,
    const float* __restrict__ fixedb,
    _Float16* __restrict__ hbuf, float* __restrict__ out, int* __restrict__ flags)
{
    const int tid  = threadIdx.x;
    const int wave = tid >> 6, lane = tid & 63;
    const int q = lane >> 4, n15 = lane & 15;
    const int blk = blockIdx.x;
    const int rg = blk >> 6, cc = blk & 63;

    half8 bw[2][4];
#pragma unroll
    for (int n = 0; n < 2; ++n) {
        const int jc = (n * 2 + (n15 >> 3)) * I_ + cc * 8 + (n15 & 7);
#pragma unroll
        for (int kc = 0; kc < 4; ++kc) {
            const int k = wave * 128 + kc * 32 + q * 8;
            const float* s0 = dWih + (size_t)jc * (H_ + I_) + H_ + k;
            const float* s1 = dWhh + (size_t)jc * I_ + k;
            float4 a0 = *(const float4*)s0, a1 = *(const float4*)(s0 + 4);
            float4 b0 = *(const float4*)s1, b1 = *(const float4*)(s1 + 4);
            bw[n][kc] = half8{(_Float16)(a0.x + b0.x), (_Float16)(a0.y + b0.y),
                              (_Float16)(a0.z + b0.z), (_Float16)(a0.w + b0.w),
                              (_Float16)(a1.x + b1.x), (_Float16)(a1.y + b1.y),
                              (_Float16)(a1.z + b1.z), (_Float16)(a1.w + b1.w)};
        }
    }

    const int hcp = tid & 3;
    const int rT  = tid >> 2;
    const int brow = rg * 64 + rT;
    float fx[4][2];
#pragma unroll
    for (int g = 0; g < 4; ++g)
#pragma unroll
        for (int e = 0; e < 2; ++e)
            fx[g][e] = fixedb[(size_t)brow * (4 * I_) + g * I_ + cc * 8 + 2 * hcp + e];
    float creg2[2] = {0.f, 0.f};

    __shared__ float preT[4][32][67];
    const size_t laneoff = (size_t)lane * 8;

    for (int s = 0; s < T_; ++s) {
        const _Float16* __restrict__ hcur = hbuf + (size_t)(s & 1) * DEC_STEP;
        _Float16* __restrict__ hnxt = hbuf + (size_t)((s + 1) & 1) * DEC_STEP;

        poll_rg(flags, rg * 64, lane, s);

        half8 Hb[4][4];
#pragma unroll
        for (int kc = 0; kc < 4; ++kc)
#pragma unroll
            for (int m = 0; m < 4; ++m)
                Hb[kc][m] = ldg_h8_sc1(hcur + ((size_t)(rg * 4 + m) * 16
                                               + (wave * 4 + kc)) * 512 + laneoff);
        floatx4 acc[4][2];
#pragma unroll
        for (int m = 0; m < 4; ++m)
#pragma unroll
            for (int n = 0; n < 2; ++n) acc[m][n] = floatx4{0.f, 0.f, 0.f, 0.f};
#pragma unroll
        for (int kc = 0; kc < 4; ++kc)
#pragma unroll
            for (int n = 0; n < 2; ++n)
#pragma unroll
                for (int m = 0; m < 4; ++m)
                    acc[m][n] = __builtin_amdgcn_mfma_f32_16x16x32_f16(
                        Hb[kc][m], bw[n][kc], acc[m][n], 0, 0, 0);

#pragma unroll
        for (int p = 0; p < 2; ++p) {
            if (p) __syncthreads();
#pragma unroll
            for (int m = 0; m < 2; ++m)
#pragma unroll
                for (int n = 0; n < 2; ++n)
#pragma unroll
                    for (int r = 0; r < 4; ++r)
                        preT[wave][n * 16 + n15][m * 16 + q * 4 + r] = acc[p * 2 + m][n][r];
            __syncthreads();
            if ((rT >> 5) == p) {
                const int rl = rT & 31;
                float pg[4][2];
#pragma unroll
                for (int g = 0; g < 4; ++g)
#pragma unroll
                    for (int e = 0; e < 2; ++e) {
                        const int col = (g >> 1) * 16 + (g & 1) * 8 + 2 * hcp + e;
                        pg[g][e] = preT[0][col][rl] + preT[1][col][rl]
                                 + preT[2][col][rl] + preT[3][col][rl] + fx[g][e];
                    }
                float hv[2];
#pragma unroll
                for (int e = 0; e < 2; ++e) {
                    const float ig = sigmoidf_(pg[0][e]);
                    const float fg = sigmoidf_(pg[1][e]);
                    const float gg = tanhf_(pg[2][e]);
                    const float og = sigmoidf_(pg[3][e]);
                    const float c  = fg * creg2[e] + ig * gg;
                    creg2[e] = c;
                    hv[e] = og * tanhf_(c);
                }
                *(float2*)(out + ((size_t)brow * T_ + (T_ - 1 - s)) * I_ + cc * 8 + 2 * hcp)
                    = float2{hv[0], hv[1]};
                const int j = cc * 8 + 2 * hcp;
                const int kch = j >> 5, j5 = j & 31;
                const int lt  = (rT & 15) | ((j5 >> 3) << 4);
                stg_h2_sc1(hnxt + ((size_t)(rg * 4 + (rT >> 4)) * 16 + kch) * 512
                                + lt * 8 + (j5 & 7), hv[0], hv[1]);
            }
        }

        wait_vm0();
        __syncthreads();
        if (tid == 0)
            __hip_atomic_store(&flags[blk], s + 1, __ATOMIC_RELAXED, __HIP_MEMORY_SCOPE_AGENT);
    }
}

// ---------------- launch ----------------
extern "C" void kernel_launch(void* const* d_in, const int* in_sizes, int n_in,
                              void* d_out_v, int out_size, void* d_ws, size_t ws_size,
                              hipStream_t stream) {
    (void)in_sizes; (void)n_in; (void)out_size;
    const float* x    = (const float*)d_in[0];
    const float* eWih = (const float*)d_in[1];
    const float* eWhh = (const float*)d_in[2];
    const float* ebih = (const float*)d_in[3];
    const float* ebhh = (const float*)d_in[4];
    const float* efcW = (const float*)d_in[5];
    const float* efcb = (const float*)d_in[6];
    const float* dfcW = (const float*)d_in[7];
    const float* dfcb = (const float*)d_in[8];
    const float* dWih = (const float*)d_in[9];
    const float* dWhh = (const float*)d_in[10];
    const float* dbih = (const float*)d_in[11];
    const float* dbhh = (const float*)d_in[12];
    float* d_out = (float*)d_out_v;

    char* ws = (char*)d_ws;
    size_t off = 0;
    auto carve = [&](size_t bytes) {
        char* p = ws + off;
        off += (bytes + 255) & ~(size_t)255;
        return p;
    };

    const size_t xf_b  = (size_t)B_ * T_ * I_ * 2;
    const size_t hbE_b = (size_t)2 * ENC_STEP * 2;          // 2-slot ring
    const size_t hbD_b = (size_t)(T_ + 1) * DEC_STEP * 2;   // 129 unique slots
    const size_t ce_b  = (size_t)B_ * H_ * 4;
    const size_t fxb_b = (size_t)B_ * 4 * I_ * 4;
    const size_t d1_b  = (size_t)B_ * H_ * 4;
    const size_t need_primary = xf_b + hbE_b + hbD_b + ce_b + fxb_b + d1_b + 8192;

    float* embd = d_out + (size_t)B_ * T_ * I_;

    if (ws_size == 0 || ws_size >= need_primary) {
        // ---------- primary: x-deferred encoder + dataflow decoder ----------
        _Float16* xf     = (_Float16*)carve(xf_b);
        _Float16* hbufE  = (_Float16*)carve(hbE_b);
        _Float16* hbufD  = (_Float16*)carve(hbD_b);
        float*    c_e    = (float*)carve(ce_b);
        float*    fixedb = (float*)carve(fxb_b);
        float*    dec1   = (float*)carve(d1_b);
        int*      flagsE = (int*)carve(256 * 4);

        hipMemsetAsync(flagsE, 0, 256 * 4, stream);
        hipMemsetAsync(hbufE, 0, (size_t)ENC_STEP * 2, stream);  // h0 = 0 (slot 0)
        // decoder: slot 0 = h0 = 0; slots 1..T poisoned with fp16 NaN
        hipMemsetAsync(hbufD, 0, (size_t)DEC_STEP * 2, stream);
        hipMemsetAsync((char*)hbufD + (size_t)DEC_STEP * 2, 0x7C, (size_t)T_ * DEC_STEP * 2, stream);

        shuffle_x_kernel<<<dim3(8192), 256, 0, stream>>>(x, xf);
        enc_xp<<<dim3(256), 256, 0, stream>>>(xf, eWih, eWhh, ebih, ebhh,
                                              hbufE, c_e, flagsE);
        small_gemm_kernel<<<dim3(E_ / 32, B_ / 32), 256, 0, stream>>>(
            c_e, H_, efcW, H_, efcb, nullptr, embd, E_, H_, 1);
        small_gemm_kernel<<<dim3(H_ / 32, B_ / 32), 256, 0, stream>>>(
            embd, E_, dfcW, E_, dfcb, nullptr, dec1, H_, E_, 1);
        small_gemm_kernel<<<dim3(4 * I_ / 32, B_ / 32), 256, 0, stream>>>(
            dec1, H_, dWih, H_ + I_, dbih, dbhh, fixedb, 4 * I_, H_, 0);
        dec_df<<<dim3(256), 256, 0, stream>>>(dWih, dWhh, fixedb, hbufD, d_out);
    } else {
        // ---------- fallback: 2-slot-ring flag protocol (round-2 verified) ----------
        _Float16* xf     = (_Float16*)carve(xf_b);
        _Float16* hbufE  = (_Float16*)carve((size_t)2 * ENC_STEP * 2);
        _Float16* hbufD  = (_Float16*)carve((size_t)2 * DEC_STEP * 2);
        float*    c_e    = (float*)carve(ce_b);
        float*    fixedb = (float*)carve(fxb_b);
        float*    dec1   = (float*)carve(d1_b);
        int*      flagsE = (int*)carve(256 * 4);
        int*      flagsD = (int*)carve(256 * 4);

        hipMemsetAsync(flagsE, 0, 256 * 4, stream);
        hipMemsetAsync(flagsD, 0, 256 * 4, stream);
        hipMemsetAsync(hbufE, 0, (size_t)ENC_STEP * 2, stream);
        hipMemsetAsync(hbufD, 0, (size_t)DEC_STEP * 2, stream);

        shuffle_x_kernel<<<dim3(8192), 256, 0, stream>>>(x, xf);
        enc_ring<<<dim3(256), 256, 0, stream>>>(xf, eWih, eWhh, ebih, ebhh,
                                                hbufE, c_e, flagsE);
        small_gemm_kernel<<<dim3(E_ / 32, B_ / 32), 256, 0, stream>>>(
            c_e, H_, efcW, H_, efcb, nullptr, embd, E_, H_, 1);
        small_gemm_kernel<<<dim3(H_ / 32, B_ / 32), 256, 0, stream>>>(
            embd, E_, dfcW, E_, dfcb, nullptr, dec1, H_, E_, 1);
        small_gemm_kernel<<<dim3(4 * I_ / 32, B_ / 32), 256, 0, stream>>>(
            dec1, H_, dWih, H_ + I_, dbih, dbhh, fixedb, 4 * I_, H_, 0);
        dec_persist<<<dim3(256), 256, 0, stream>>>(dWih, dWhh, fixedb,
                                                   hbufD, d_out, flagsD);
    }
}

// Round 7
// 1687.562 us; speedup vs baseline: 2.0195x; 1.3545x over previous
//
#include <hip/hip_runtime.h>
#include <hip/hip_fp16.h>

// LSTM Autoencoder: B=256, T=128, I=512, H=1024, E=256
// Round-8 resubmit (round-6 bench died on container acquisition, no data):
// bank the verified round-2 encoder (884us, verbatim); apply the traffic
// lever to the DECODER where registers fit:
//   dec_df2: 4 rg x 32 cc (128 blocks), each block covers 16 h-cols
//   (64 gate-cols). Per-step coherent traffic 16->8 MB, consumers/rg 64->32.
//   bw[4][4]+Hb[4][4]+acc[4][4] ~ 250 VGPR -- no liveness cliff (rounds 4/5
//   lesson: restructures die when a new live register group pushes past the
//   allocator's budget; 512-thr blocks cap at 256 VGPR).
//   Epilogue = encoder's verified 2-phase preT scheme (all threads, rT 0..31).
//   Protocol = measured-good dataflow sentinel (129 slots, optimistic loads).

#define B_ 256
#define T_ 128
#define I_ 512
#define H_ 1024
#define E_ 256

#define ENC_STEP 262144   // fp16 elems per encoder h slot (256x1024)
#define DEC_STEP 131072   // fp16 elems per decoder h slot (256x512)
#define SENT32 0x7C7C7C7Cu   // two fp16 NaNs; unreachable by real h pairs

typedef _Float16 half8 __attribute__((ext_vector_type(8)));
typedef float floatx4 __attribute__((ext_vector_type(4)));

__device__ __forceinline__ float sigmoidf_(float x) { return 1.0f / (1.0f + __expf(-x)); }
__device__ __forceinline__ float tanhf_(float x) {
    x = fminf(fmaxf(x, -15.0f), 15.0f);
    float e = __expf(2.0f * x);
    return (e - 1.0f) / (e + 1.0f);
}

union HU { unsigned long long u[2]; unsigned v[4]; half8 h; };

// coherent 16B load as 2x u64 relaxed-agent atomics (global_load_dwordx2 sc0 sc1)
__device__ __forceinline__ void ld_chunk(const _Float16* p, HU& v) {
    const unsigned long long* q = (const unsigned long long*)p;
    v.u[0] = __hip_atomic_load(q,     __ATOMIC_RELAXED, __HIP_MEMORY_SCOPE_AGENT);
    v.u[1] = __hip_atomic_load(q + 1, __ATOMIC_RELAXED, __HIP_MEMORY_SCOPE_AGENT);
}
__device__ __forceinline__ int chunk_ok(const HU& v) {
    return (int)((v.v[0] != SENT32) & (v.v[1] != SENT32)
               & (v.v[2] != SENT32) & (v.v[3] != SENT32));
}
template <int STRIDE>
__device__ __forceinline__ void load_grp(const _Float16* base, HU v[4]) {
#pragma unroll
    for (int m = 0; m < 4; ++m) ld_chunk(base + (size_t)m * STRIDE, v[m]);
}
template <int STRIDE>
__device__ __forceinline__ void fix_grp(const _Float16* base, HU v[4]) {
    while (!(chunk_ok(v[0]) & chunk_ok(v[1]) & chunk_ok(v[2]) & chunk_ok(v[3]))) {
        __builtin_amdgcn_s_sleep(1);
        load_grp<STRIDE>(base, v);
    }
}

__device__ __forceinline__ half8 ldg_h8_sc1(const _Float16* p) {
    HU v; ld_chunk(p, v); return v.h;
}
__device__ __forceinline__ void stg_h2_sc1(_Float16* p, float a, float b) {
    union { _Float16 h[2]; unsigned int u; } v;
    v.h[0] = (_Float16)a; v.h[1] = (_Float16)b;
    __hip_atomic_store((unsigned int*)p, v.u, __ATOMIC_RELAXED, __HIP_MEMORY_SCOPE_AGENT);
}
__device__ __forceinline__ void wait_vm0() {
    asm volatile("s_waitcnt vmcnt(0)" ::: "memory");
}
__device__ __forceinline__ void poll_rg(int* flags, int rgbase, int lane, int target) {
    while (__hip_atomic_load(&flags[rgbase + lane], __ATOMIC_RELAXED, __HIP_MEMORY_SCOPE_AGENT) < target)
        __builtin_amdgcn_s_sleep(1);
    asm volatile("" ::: "memory");
}

// ---------------- x -> MFMA A-fragment layout (once) ----------------
__global__ void shuffle_x_kernel(const float* __restrict__ x, _Float16* __restrict__ xf) {
    const int gg   = blockIdx.x * 256 + threadIdx.x;
    const int tile = gg >> 6;
    const int lane = gg & 63;
    const int t  = tile >> 8;
    const int rt = (tile >> 4) & 15;
    const int kc = tile & 15;
    const int b  = rt * 16 + (lane & 15);
    const int j0 = kc * 32 + ((lane >> 4) << 3);
    const float* src = x + ((size_t)b * T_ + t) * I_ + j0;
    float4 f0 = *(const float4*)src;
    float4 f1 = *(const float4*)(src + 4);
    half8 h = { (_Float16)f0.x, (_Float16)f0.y, (_Float16)f0.z, (_Float16)f0.w,
                (_Float16)f1.x, (_Float16)f1.y, (_Float16)f1.z, (_Float16)f1.w };
    *(half8*)(xf + (size_t)tile * 512 + lane * 8) = h;
}

// ---------------- small fp32 GEMM ----------------
__global__ __launch_bounds__(256) void small_gemm_kernel(
    const float* __restrict__ A, int lda,
    const float* __restrict__ W, int ldw,
    const float* __restrict__ b1, const float* __restrict__ b2,
    float* __restrict__ out, int N, int K, int relu)
{
    __shared__ float sA2[32][33];
    __shared__ float sW2[32][33];
    int tid = threadIdx.x;
    int tx = tid & 15, ty = tid >> 4;
    int m0 = blockIdx.y * 32, n0 = blockIdx.x * 32;
    float acc[2][2] = {};
    for (int k0 = 0; k0 < K; k0 += 32) {
        __syncthreads();
#pragma unroll
        for (int i = 0; i < 4; ++i) {
            int e = tid + i * 256;
            int r = e >> 5, c = e & 31;
            sA2[r][c] = A[(size_t)(m0 + r) * lda + k0 + c];
            sW2[r][c] = W[(size_t)(n0 + r) * ldw + k0 + c];
        }
        __syncthreads();
#pragma unroll
        for (int k = 0; k < 32; ++k) {
            float a0 = sA2[ty * 2][k], a1 = sA2[ty * 2 + 1][k];
            float w0 = sW2[tx * 2][k], w1 = sW2[tx * 2 + 1][k];
            acc[0][0] += a0 * w0; acc[0][1] += a0 * w1;
            acc[1][0] += a1 * w0; acc[1][1] += a1 * w1;
        }
    }
#pragma unroll
    for (int i = 0; i < 2; ++i)
#pragma unroll
        for (int j = 0; j < 2; ++j) {
            int m = m0 + ty * 2 + i, n = n0 + tx * 2 + j;
            float v = acc[i][j] + b1[n] + (b2 ? b2[n] : 0.0f);
            if (relu) v = fmaxf(v, 0.0f);
            out[(size_t)m * N + n] = v;
        }
}

// ================= encoder: round-2 VERIFIED kernel, verbatim (884 us) =================
// grid 256 = 4 row-groups (64 batch rows) x 64 col-CUs (16 h-cols -> 64 gate-cols)
// flags[blk] counts wave drains: block done with step s <=> flags[blk]==4*(s+1).
__global__ __launch_bounds__(256, 1) void enc_persist(
    const _Float16* __restrict__ xf,
    const float* __restrict__ Wih, const float* __restrict__ Whh,
    const float* __restrict__ bih, const float* __restrict__ bhh,
    _Float16* __restrict__ hbuf, float* __restrict__ c_out, int* __restrict__ flags)
{
    const int tid  = threadIdx.x;
    const int wave = tid >> 6, lane = tid & 63;
    const int q = lane >> 4, n15 = lane & 15;
    const int blk = blockIdx.x;
    const int rg = blk >> 6, cc = blk & 63;

    // weights -> VGPRs (192 regs/lane)
    half8 bw[4][12];
#pragma unroll
    for (int g = 0; g < 4; ++g) {
        const int jc = g * H_ + cc * 16 + n15;
#pragma unroll
        for (int kc = 0; kc < 12; ++kc) {
            const int k = (4 * kc + wave) * 32 + q * 8;
            const float* src = (k < I_) ? (Wih + (size_t)jc * I_ + k)
                                        : (Whh + (size_t)jc * H_ + (k - I_));
            float4 f0 = *(const float4*)src;
            float4 f1 = *(const float4*)(src + 4);
            bw[g][kc] = half8{(_Float16)f0.x, (_Float16)f0.y, (_Float16)f0.z, (_Float16)f0.w,
                              (_Float16)f1.x, (_Float16)f1.y, (_Float16)f1.z, (_Float16)f1.w};
        }
    }

    const int hcp = tid & 7;    // owned col-pair (2*hcp, 2*hcp+1)
    const int rT  = tid >> 3;   // owned row (phase A: rT, phase B: 32+rT)
    float breg[4][2];
#pragma unroll
    for (int g = 0; g < 4; ++g)
#pragma unroll
        for (int e = 0; e < 2; ++e) {
            const int j = g * H_ + cc * 16 + 2 * hcp + e;
            breg[g][e] = bih[j] + bhh[j];
        }
    float creg[2][2] = {{0.f, 0.f}, {0.f, 0.f}};

    __shared__ float preT[4][64][35];
    const size_t laneoff = (size_t)lane * 8;

    for (int s = 0; s < T_; ++s) {
        const _Float16* __restrict__ hcur = hbuf + (size_t)(s & 1) * ENC_STEP;
        _Float16* __restrict__ hnxt = hbuf + (size_t)((s + 1) & 1) * ENC_STEP;

        floatx4 acc[4][4];
#pragma unroll
        for (int m = 0; m < 4; ++m)
#pragma unroll
            for (int n = 0; n < 4; ++n) acc[m][n] = floatx4{0.f, 0.f, 0.f, 0.f};

        // ---- x loads + first half of x-MFMAs (hides producer lag)
        half8 X[4][4];
#pragma unroll
        for (int kc = 0; kc < 4; ++kc)
#pragma unroll
            for (int m = 0; m < 4; ++m)
                X[kc][m] = *(const half8*)(xf + (((size_t)s * 16 + rg * 4 + m) * 16
                                                + (4 * kc + wave)) * 512 + laneoff);
#pragma unroll
        for (int kc = 0; kc < 2; ++kc)
#pragma unroll
            for (int n = 0; n < 4; ++n)
#pragma unroll
                for (int m = 0; m < 4; ++m)
                    acc[m][n] = __builtin_amdgcn_mfma_f32_16x16x32_f16(
                        X[kc][m], bw[n][kc], acc[m][n], 0, 0, 0);

        // ---- wait for h_s: all 64 blocks of rg have all 4 waves drained
        poll_rg(flags, rg * 64, lane, 4 * s);

        // ---- issue first 4 h-load groups immediately after the poll
        half8 Hb[4][4];
#pragma unroll
        for (int kc = 4; kc < 8; ++kc)
#pragma unroll
            for (int m = 0; m < 4; ++m)
                Hb[kc - 4][m] = ldg_h8_sc1(hcur + ((size_t)(rg * 4 + m) * 32
                                                   + (4 * kc + wave - 16)) * 512 + laneoff);

        // ---- second half of x-MFMAs covers the first h group's LLC RT
#pragma unroll
        for (int kc = 2; kc < 4; ++kc)
#pragma unroll
            for (int n = 0; n < 4; ++n)
#pragma unroll
                for (int m = 0; m < 4; ++m)
                    acc[m][n] = __builtin_amdgcn_mfma_f32_16x16x32_f16(
                        X[kc][m], bw[n][kc], acc[m][n], 0, 0, 0);

        // ---- h phase: depth-4 pipelined sc1 loads + 128 MFMAs
#pragma unroll
        for (int kc = 4; kc < 12; ++kc) {
            const int sl = kc & 3;
#pragma unroll
            for (int n = 0; n < 4; ++n)
#pragma unroll
                for (int m = 0; m < 4; ++m)
                    acc[m][n] = __builtin_amdgcn_mfma_f32_16x16x32_f16(
                        Hb[sl][m], bw[n][kc], acc[m][n], 0, 0, 0);
            if (kc < 8) {
#pragma unroll
                for (int m = 0; m < 4; ++m)
                    Hb[sl][m] = ldg_h8_sc1(hcur + ((size_t)(rg * 4 + m) * 32
                                                   + (4 * (kc + 4) + wave - 16)) * 512 + laneoff);
            }
        }

        // ---- epilogue: 2 phases (rows 0..31, 32..63)
#pragma unroll
        for (int p = 0; p < 2; ++p) {
            if (p) __syncthreads();   // phase-A reads done before phase-B writes
#pragma unroll
            for (int m = 0; m < 2; ++m)
#pragma unroll
                for (int n = 0; n < 4; ++n)
#pragma unroll
                    for (int r = 0; r < 4; ++r)
                        preT[wave][n * 16 + n15][m * 16 + q * 4 + r] = acc[p * 2 + m][n][r];
            __syncthreads();
            float pg[4][2];
#pragma unroll
            for (int g = 0; g < 4; ++g)
#pragma unroll
                for (int e = 0; e < 2; ++e) {
                    const int col = g * 16 + 2 * hcp + e;
                    pg[g][e] = preT[0][col][rT] + preT[1][col][rT]
                             + preT[2][col][rT] + preT[3][col][rT] + breg[g][e];
                }
            float hv[2];
#pragma unroll
            for (int e = 0; e < 2; ++e) {
                const float ig = sigmoidf_(pg[0][e]);
                const float fg = sigmoidf_(pg[1][e]);
                const float gg = tanhf_(pg[2][e]);
                const float og = sigmoidf_(pg[3][e]);
                const float c  = fg * creg[p][e] + ig * gg;
                creg[p][e] = c;
                hv[e] = og * tanhf_(c);
            }
            const int row = p * 32 + rT;
            const int j   = cc * 16 + 2 * hcp;
            const int kch = j >> 5, j5 = j & 31;
            const int lt  = (row & 15) | ((j5 >> 3) << 4);
            stg_h2_sc1(hnxt + ((size_t)(rg * 4 + (row >> 4)) * 32 + kch) * 512
                            + lt * 8 + (j5 & 7), hv[0], hv[1]);
        }

        // ---- barrier-free publication: per-wave drain + count
        wait_vm0();
        if (lane == 0)
            __hip_atomic_fetch_add(&flags[blk], 1, __ATOMIC_RELAXED, __HIP_MEMORY_SCOPE_AGENT);
        __syncthreads();     // preT reuse protection (off the inter-block path)
    }

    // final cell state (plain stores; visible via kernel-end release)
#pragma unroll
    for (int p = 0; p < 2; ++p)
        *(float2*)(c_out + (size_t)(rg * 64 + p * 32 + rT) * H_ + cc * 16 + 2 * hcp)
            = float2{creg[p][0], creg[p][1]};
}

// ================= decoder v2: 4 rg x 32 cc (128 blocks), dataflow sentinel =================
// block (rg, cc): rows rg*64..+63, h-cols cc*16..+16 -> gate-cols {g*512+cc*16+j}.
// Wave w owns K chunks w*4+kc (kc=0..3), K=512. Same h layout/loads as old dec_df;
// traffic halves because block count halves (32 consumers/rg, was 64).
__global__ __launch_bounds__(256, 1) void dec_df2(
    const float* __restrict__ dWih, const float* __restrict__ dWhh,
    const float* __restrict__ fixedb,
    _Float16* __restrict__ hbuf, float* __restrict__ out)
{
    const int tid  = threadIdx.x;
    const int wave = tid >> 6, lane = tid & 63;
    const int q = lane >> 4, n15 = lane & 15;
    const int blk = blockIdx.x;
    const int rg = blk >> 5;    // 0..3
    const int cc = blk & 31;    // 0..31

    // W_rec = dWih[:,H:] + dWhh -> VGPRs: bw[gate][kc], 64 regs
    half8 bw[4][4];
#pragma unroll
    for (int n = 0; n < 4; ++n) {
        const int jc = n * I_ + cc * 16 + n15;
#pragma unroll
        for (int kc = 0; kc < 4; ++kc) {
            const int k = wave * 128 + kc * 32 + q * 8;
            const float* s0 = dWih + (size_t)jc * (H_ + I_) + H_ + k;
            const float* s1 = dWhh + (size_t)jc * I_ + k;
            float4 a0 = *(const float4*)s0, a1 = *(const float4*)(s0 + 4);
            float4 b0 = *(const float4*)s1, b1 = *(const float4*)(s1 + 4);
            bw[n][kc] = half8{(_Float16)(a0.x + b0.x), (_Float16)(a0.y + b0.y),
                              (_Float16)(a0.z + b0.z), (_Float16)(a0.w + b0.w),
                              (_Float16)(a1.x + b1.x), (_Float16)(a1.y + b1.y),
                              (_Float16)(a1.z + b1.z), (_Float16)(a1.w + b1.w)};
        }
    }

    const int hcp = tid & 7;    // owned col-pair (2*hcp, 2*hcp+1) within 16 h-cols
    const int rT  = tid >> 3;   // owned rows rT (p=0), 32+rT (p=1)
    float fx[2][4][2];
#pragma unroll
    for (int p = 0; p < 2; ++p)
#pragma unroll
        for (int g = 0; g < 4; ++g)
#pragma unroll
            for (int e = 0; e < 2; ++e)
                fx[p][g][e] = fixedb[(size_t)(rg * 64 + p * 32 + rT) * (4 * I_)
                                     + g * I_ + cc * 16 + 2 * hcp + e];
    float creg2[2][2] = {{0.f, 0.f}, {0.f, 0.f}};

    __shared__ float preT[4][64][35];
    const size_t laneoff = (size_t)lane * 8;

    for (int s = 0; s < T_; ++s) {
        const _Float16* __restrict__ hcur = hbuf + (size_t)s * DEC_STEP;
        _Float16* __restrict__ hnxt = hbuf + (size_t)(s + 1) * DEC_STEP;

        // optimistic sc1 loads: rows m*16.., K chunk wave*4+kc (identical
        // addressing to the measured dec_df; 16 chunks/lane = 64 KB/block)
        HU Hb[4][4];
#pragma unroll
        for (int kc = 0; kc < 4; ++kc)
            load_grp<16 * 512>(hcur + ((size_t)(rg * 4) * 16 + (wave * 4 + kc)) * 512
                                    + laneoff, Hb[kc]);

        floatx4 acc[4][4];
#pragma unroll
        for (int m = 0; m < 4; ++m)
#pragma unroll
            for (int n = 0; n < 4; ++n) acc[m][n] = floatx4{0.f, 0.f, 0.f, 0.f};
#pragma unroll
        for (int kc = 0; kc < 4; ++kc) {
            fix_grp<16 * 512>(hcur + ((size_t)(rg * 4) * 16 + (wave * 4 + kc)) * 512
                                   + laneoff, Hb[kc]);
#pragma unroll
            for (int n = 0; n < 4; ++n)
#pragma unroll
                for (int m = 0; m < 4; ++m)
                    acc[m][n] = __builtin_amdgcn_mfma_f32_16x16x32_f16(
                        Hb[kc][m].h, bw[n][kc], acc[m][n], 0, 0, 0);
        }

        // ---- epilogue: encoder's verified 2-phase scheme
#pragma unroll
        for (int p = 0; p < 2; ++p) {
            if (p) __syncthreads();
#pragma unroll
            for (int m = 0; m < 2; ++m)
#pragma unroll
                for (int n = 0; n < 4; ++n)
#pragma unroll
                    for (int r = 0; r < 4; ++r)
                        preT[wave][n * 16 + n15][m * 16 + q * 4 + r] = acc[p * 2 + m][n][r];
            __syncthreads();
            float pg[4][2];
#pragma unroll
            for (int g = 0; g < 4; ++g)
#pragma unroll
                for (int e = 0; e < 2; ++e) {
                    const int col = g * 16 + 2 * hcp + e;
                    pg[g][e] = preT[0][col][rT] + preT[1][col][rT]
                             + preT[2][col][rT] + preT[3][col][rT] + fx[p][g][e];
                }
            float hv[2];
#pragma unroll
            for (int e = 0; e < 2; ++e) {
                const float ig = sigmoidf_(pg[0][e]);
                const float fg = sigmoidf_(pg[1][e]);
                const float gg = tanhf_(pg[2][e]);
                const float og = sigmoidf_(pg[3][e]);
                const float c  = fg * creg2[p][e] + ig * gg;
                creg2[p][e] = c;
                hv[e] = og * tanhf_(c);
            }
            const int row = p * 32 + rT;
            *(float2*)(out + ((size_t)(rg * 64 + row) * T_ + (T_ - 1 - s)) * I_
                           + cc * 16 + 2 * hcp) = float2{hv[0], hv[1]};
            const int j   = cc * 16 + 2 * hcp;
            const int kch = j >> 5, j5 = j & 31;
            const int lt  = (row & 15) | ((j5 >> 3) << 4);
            stg_h2_sc1(hnxt + ((size_t)(rg * 4 + (row >> 4)) * 16 + kch) * 512
                            + lt * 8 + (j5 & 7), hv[0], hv[1]);
        }
        __syncthreads();   // preT reuse (fire-and-forget stores: dataflow)
    }
}

// ================= FALLBACK decoder (flag protocol, 2-slot ring, tiny ws) =================
__global__ __launch_bounds__(256, 1) void dec_persist(
    const float* __restrict__ dWih, const float* __restrict__ dWhh,
    const float* __restrict__ fixedb,
    _Float16* __restrict__ hbuf, float* __restrict__ out, int* __restrict__ flags)
{
    const int tid  = threadIdx.x;
    const int wave = tid >> 6, lane = tid & 63;
    const int q = lane >> 4, n15 = lane & 15;
    const int blk = blockIdx.x;
    const int rg = blk >> 6, cc = blk & 63;

    half8 bw[2][4];
#pragma unroll
    for (int n = 0; n < 2; ++n) {
        const int jc = (n * 2 + (n15 >> 3)) * I_ + cc * 8 + (n15 & 7);
#pragma unroll
        for (int kc = 0; kc < 4; ++kc) {
            const int k = wave * 128 + kc * 32 + q * 8;
            const float* s0 = dWih + (size_t)jc * (H_ + I_) + H_ + k;
            const float* s1 = dWhh + (size_t)jc * I_ + k;
            float4 a0 = *(const float4*)s0, a1 = *(const float4*)(s0 + 4);
            float4 b0 = *(const float4*)s1, b1 = *(const float4*)(s1 + 4);
            bw[n][kc] = half8{(_Float16)(a0.x + b0.x), (_Float16)(a0.y + b0.y),
                              (_Float16)(a0.z + b0.z), (_Float16)(a0.w + b0.w),
                              (_Float16)(a1.x + b1.x), (_Float16)(a1.y + b1.y),
                              (_Float16)(a1.z + b1.z), (_Float16)(a1.w + b1.w)};
        }
    }

    const int hcp = tid & 3;
    const int rT  = tid >> 2;
    const int brow = rg * 64 + rT;
    float fx[4][2];
#pragma unroll
    for (int g = 0; g < 4; ++g)
#pragma unroll
        for (int e = 0; e < 2; ++e)
            fx[g][e] = fixedb[(size_t)brow * (4 * I_) + g * I_ + cc * 8 + 2 * hcp + e];
    float creg2[2] = {0.f, 0.f};

    __shared__ float preT[4][32][67];
    const size_t laneoff = (size_t)lane * 8;

    for (int s = 0; s < T_; ++s) {
        const _Float16* __restrict__ hcur = hbuf + (size_t)(s & 1) * DEC_STEP;
        _Float16* __restrict__ hnxt = hbuf + (size_t)((s + 1) & 1) * DEC_STEP;

        poll_rg(flags, rg * 64, lane, s);

        half8 Hb[4][4];
#pragma unroll
        for (int kc = 0; kc < 4; ++kc)
#pragma unroll
            for (int m = 0; m < 4; ++m)
                Hb[kc][m] = ldg_h8_sc1(hcur + ((size_t)(rg * 4 + m) * 16
                                               + (wave * 4 + kc)) * 512 + laneoff);
        floatx4 acc[4][2];
#pragma unroll
        for (int m = 0; m < 4; ++m)
#pragma unroll
            for (int n = 0; n < 2; ++n) acc[m][n] = floatx4{0.f, 0.f, 0.f, 0.f};
#pragma unroll
        for (int kc = 0; kc < 4; ++kc)
#pragma unroll
            for (int n = 0; n < 2; ++n)
#pragma unroll
                for (int m = 0; m < 4; ++m)
                    acc[m][n] = __builtin_amdgcn_mfma_f32_16x16x32_f16(
                        Hb[kc][m], bw[n][kc], acc[m][n], 0, 0, 0);

#pragma unroll
        for (int p = 0; p < 2; ++p) {
            if (p) __syncthreads();
#pragma unroll
            for (int m = 0; m < 2; ++m)
#pragma unroll
                for (int n = 0; n < 2; ++n)
#pragma unroll
                    for (int r = 0; r < 4; ++r)
                        preT[wave][n * 16 + n15][m * 16 + q * 4 + r] = acc[p * 2 + m][n][r];
            __syncthreads();
            if ((rT >> 5) == p) {
                const int rl = rT & 31;
                float pg[4][2];
#pragma unroll
                for (int g = 0; g < 4; ++g)
#pragma unroll
                    for (int e = 0; e < 2; ++e) {
                        const int col = (g >> 1) * 16 + (g & 1) * 8 + 2 * hcp + e;
                        pg[g][e] = preT[0][col][rl] + preT[1][col][rl]
                                 + preT[2][col][rl] + preT[3][col][rl] + fx[g][e];
                    }
                float hv[2];
#pragma unroll
                for (int e = 0; e < 2; ++e) {
                    const float ig = sigmoidf_(pg[0][e]);
                    const float fg = sigmoidf_(pg[1][e]);
                    const float gg = tanhf_(pg[2][e]);
                    const float og = sigmoidf_(pg[3][e]);
                    const float c  = fg * creg2[e] + ig * gg;
                    creg2[e] = c;
                    hv[e] = og * tanhf_(c);
                }
                *(float2*)(out + ((size_t)brow * T_ + (T_ - 1 - s)) * I_ + cc * 8 + 2 * hcp)
                    = float2{hv[0], hv[1]};
                const int j = cc * 8 + 2 * hcp;
                const int kch = j >> 5, j5 = j & 31;
                const int lt  = (rT & 15) | ((j5 >> 3) << 4);
                stg_h2_sc1(hnxt + ((size_t)(rg * 4 + (rT >> 4)) * 16 + kch) * 512
                                + lt * 8 + (j5 & 7), hv[0], hv[1]);
            }
        }

        wait_vm0();
        __syncthreads();
        if (tid == 0)
            __hip_atomic_store(&flags[blk], s + 1, __ATOMIC_RELAXED, __HIP_MEMORY_SCOPE_AGENT);
    }
}

// ---------------- launch ----------------
extern "C" void kernel_launch(void* const* d_in, const int* in_sizes, int n_in,
                              void* d_out_v, int out_size, void* d_ws, size_t ws_size,
                              hipStream_t stream) {
    (void)in_sizes; (void)n_in; (void)out_size;
    const float* x    = (const float*)d_in[0];
    const float* eWih = (const float*)d_in[1];
    const float* eWhh = (const float*)d_in[2];
    const float* ebih = (const float*)d_in[3];
    const float* ebhh = (const float*)d_in[4];
    const float* efcW = (const float*)d_in[5];
    const float* efcb = (const float*)d_in[6];
    const float* dfcW = (const float*)d_in[7];
    const float* dfcb = (const float*)d_in[8];
    const float* dWih = (const float*)d_in[9];
    const float* dWhh = (const float*)d_in[10];
    const float* dbih = (const float*)d_in[11];
    const float* dbhh = (const float*)d_in[12];
    float* d_out = (float*)d_out_v;

    char* ws = (char*)d_ws;
    size_t off = 0;
    auto carve = [&](size_t bytes) {
        char* p = ws + off;
        off += (bytes + 255) & ~(size_t)255;
        return p;
    };

    const size_t xf_b  = (size_t)B_ * T_ * I_ * 2;
    const size_t hbE_b = (size_t)2 * ENC_STEP * 2;          // 2-slot ring (flags)
    const size_t hbD_b = (size_t)(T_ + 1) * DEC_STEP * 2;   // 129 slots (dataflow)
    const size_t ce_b  = (size_t)B_ * H_ * 4;
    const size_t fxb_b = (size_t)B_ * 4 * I_ * 4;
    const size_t d1_b  = (size_t)B_ * H_ * 4;
    const size_t need_primary = xf_b + hbE_b + hbD_b + ce_b + fxb_b + d1_b + 8192;

    float* embd = d_out + (size_t)B_ * T_ * I_;

    if (ws_size == 0 || ws_size >= need_primary) {
        // ---------- primary: round-2 encoder + halved-group dataflow decoder ----------
        _Float16* xf     = (_Float16*)carve(xf_b);
        _Float16* hbufE  = (_Float16*)carve(hbE_b);
        _Float16* hbufD  = (_Float16*)carve(hbD_b);
        float*    c_e    = (float*)carve(ce_b);
        float*    fixedb = (float*)carve(fxb_b);
        float*    dec1   = (float*)carve(d1_b);
        int*      flagsE = (int*)carve(256 * 4);

        hipMemsetAsync(flagsE, 0, 256 * 4, stream);
        hipMemsetAsync(hbufE, 0, (size_t)ENC_STEP * 2, stream);  // h0 = 0 (slot 0)
        // decoder: slot 0 = h0 = 0; slots 1..T poisoned with fp16 NaN
        hipMemsetAsync(hbufD, 0, (size_t)DEC_STEP * 2, stream);
        hipMemsetAsync((char*)hbufD + (size_t)DEC_STEP * 2, 0x7C, (size_t)T_ * DEC_STEP * 2, stream);

        shuffle_x_kernel<<<dim3(8192), 256, 0, stream>>>(x, xf);
        enc_persist<<<dim3(256), 256, 0, stream>>>(xf, eWih, eWhh, ebih, ebhh,
                                                   hbufE, c_e, flagsE);
        small_gemm_kernel<<<dim3(E_ / 32, B_ / 32), 256, 0, stream>>>(
            c_e, H_, efcW, H_, efcb, nullptr, embd, E_, H_, 1);
        small_gemm_kernel<<<dim3(H_ / 32, B_ / 32), 256, 0, stream>>>(
            embd, E_, dfcW, E_, dfcb, nullptr, dec1, H_, E_, 1);
        small_gemm_kernel<<<dim3(4 * I_ / 32, B_ / 32), 256, 0, stream>>>(
            dec1, H_, dWih, H_ + I_, dbih, dbhh, fixedb, 4 * I_, H_, 0);
        dec_df2<<<dim3(128), 256, 0, stream>>>(dWih, dWhh, fixedb, hbufD, d_out);
    } else {
        // ---------- fallback: 2-slot-ring flag protocol both ----------
        _Float16* xf     = (_Float16*)carve(xf_b);
        _Float16* hbufE  = (_Float16*)carve((size_t)2 * ENC_STEP * 2);
        _Float16* hbufD  = (_Float16*)carve((size_t)2 * DEC_STEP * 2);
        float*    c_e    = (float*)carve(ce_b);
        float*    fixedb = (float*)carve(fxb_b);
        float*    dec1   = (float*)carve(d1_b);
        int*      flagsE = (int*)carve(256 * 4);
        int*      flagsD = (int*)carve(256 * 4);

        hipMemsetAsync(flagsE, 0, 256 * 4, stream);
        hipMemsetAsync(flagsD, 0, 256 * 4, stream);
        hipMemsetAsync(hbufE, 0, (size_t)ENC_STEP * 2, stream);
        hipMemsetAsync(hbufD, 0, (size_t)DEC_STEP * 2, stream);

        shuffle_x_kernel<<<dim3(8192), 256, 0, stream>>>(x, xf);
        enc_persist<<<dim3(256), 256, 0, stream>>>(xf, eWih, eWhh, ebih, ebhh,
                                                   hbufE, c_e, flagsE);
        small_gemm_kernel<<<dim3(E_ / 32, B_ / 32), 256, 0, stream>>>(
            c_e, H_, efcW, H_, efcb, nullptr, embd, E_, H_, 1);
        small_gemm_kernel<<<dim3(H_ / 32, B_ / 32), 256, 0, stream>>>(
            embd, E_, dfcW, E_, dfcb, nullptr, dec1, H_, E_, 1);
        small_gemm_kernel<<<dim3(4 * I_ / 32, B_ / 32), 256, 0, stream>>>(
            dec1, H_, dWih, H_ + I_, dbih, dbhh, fixedb, 4 * I_, H_, 0);
        dec_persist<<<dim3(256), 256, 0, stream>>>(dWih, dWhh, fixedb,
                                                   hbufD, d_out, flagsD);
    }
}